// Round 1
// baseline (478.450 us; speedup 1.0000x reference)
//
#include <hip/hip_runtime.h>
#include <cstdint>

#define NCOARSE 4000
#define NFINE   40000
#define DIM     128
#define SEGN    2000   // coarse points per wave-segment (2 segments per block)

__device__ __forceinline__ uint64_t min64(uint64_t a, uint64_t b) { return a < b ? a : b; }
__device__ __forceinline__ uint64_t max64(uint64_t a, uint64_t b) { return a > b ? a : b; }

// One block = 128 threads = 2 waves, handles 64 fine points.
// Wave 0 scans coarse [0,2000), wave 1 scans [2000,4000); per-lane exact top-7
// by key (f32 d2 bits << 32 | coarse_idx)  -> unique keys, strict total order.
__global__ __launch_bounds__(128) void upsampler_fused(
    const float* __restrict__ xc,    // [4000][128]
    const float* __restrict__ pc,    // [4000][3]
    const float* __restrict__ pf,    // [40000][3]
    const float* __restrict__ W,     // [128][128]
    const float* __restrict__ bias,  // [128]
    float* __restrict__ out)         // [40000][128]
{
    __shared__ uint64_t pairs[2][64][7];   // per-segment sorted top-7 per fine point
    __shared__ int      idx6[64][6];       // final 6 neighbor indices
    __shared__ float    interp[64][DIM];   // sum of 6 gathered rows (scaled by 1/6 later)

    const int tid   = threadIdx.x;
    const int lane  = tid & 63;
    const int seg   = tid >> 6;            // wave-uniform: 0 or 1
    const int fbase = blockIdx.x * 64;

    // ---------------- Phase 1: per-lane top-7 over this wave's coarse segment
    {
        const int f  = fbase + lane;
        const float fx = pf[f * 3 + 0];
        const float fy = pf[f * 3 + 1];
        const float fz = pf[f * 3 + 2];
        uint64_t a0 = ~0ull, a1 = ~0ull, a2 = ~0ull, a3 = ~0ull,
                 a4 = ~0ull, a5 = ~0ull, a6 = ~0ull;
        const int c0 = seg * SEGN;
        #pragma unroll 4
        for (int c = c0; c < c0 + SEGN; ++c) {
            // c is wave-uniform -> compiler emits scalar loads for pos_coarse
            const float cx = pc[c * 3 + 0];
            const float cy = pc[c * 3 + 1];
            const float cz = pc[c * 3 + 2];
            // EXACT numpy arithmetic: no FMA contraction, left-to-right sum
            const float dx = __fsub_rn(fx, cx);
            const float dy = __fsub_rn(fy, cy);
            const float dz = __fsub_rn(fz, cz);
            const float d2 = __fadd_rn(__fadd_rn(__fmul_rn(dx, dx), __fmul_rn(dy, dy)),
                                       __fmul_rn(dz, dz));
            const uint64_t v = ((uint64_t)__float_as_uint(d2) << 32) | (uint32_t)c;
            if (v < a6) {   // guarded branchless insertion network (sorted ascending)
                a6 = min64(a6, max64(a5, v));
                a5 = min64(a5, max64(a4, v));
                a4 = min64(a4, max64(a3, v));
                a3 = min64(a3, max64(a2, v));
                a2 = min64(a2, max64(a1, v));
                a1 = min64(a1, max64(a0, v));
                a0 = min64(a0, v);
            }
        }
        pairs[seg][lane][0] = a0; pairs[seg][lane][1] = a1; pairs[seg][lane][2] = a2;
        pairs[seg][lane][3] = a3; pairs[seg][lane][4] = a4; pairs[seg][lane][5] = a5;
        pairs[seg][lane][6] = a6;
    }
    __syncthreads();

    // ---------------- Phase 2: merge the two sorted 7-lists, sqrt tie repair
    if (tid < 64) {
        int p = 0, q = 0;
        uint64_t m0, m1, m2, m3, m4, m5, m6;
        #define PICK(mr) { \
            const uint64_t va = pairs[0][tid][p]; \
            const uint64_t vb = pairs[1][tid][q]; \
            const bool ta = va < vb; \
            mr = ta ? va : vb; \
            p += ta ? 1 : 0; q += ta ? 0 : 1; }
        PICK(m0) PICK(m1) PICK(m2) PICK(m3) PICK(m4) PICK(m5) PICK(m6)
        #undef PICK
        // Reference sorts by sqrt(d2) (f32, correctly rounded), ties broken by
        // smaller index (stable argsort). Our (d2,idx) order can differ from
        // (sqrt(d2),idx) order only when two d2 collapse to the same f32 sqrt
        // at the 6th/7th boundary — repair membership in that case.
        int i5 = (int)(uint32_t)m5;
        const int i6 = (int)(uint32_t)m6;
        const float d5 = sqrtf(__uint_as_float((uint32_t)(m5 >> 32)));
        const float d6 = sqrtf(__uint_as_float((uint32_t)(m6 >> 32)));
        if (d5 == d6 && i6 < i5) i5 = i6;
        idx6[tid][0] = (int)(uint32_t)m0;
        idx6[tid][1] = (int)(uint32_t)m1;
        idx6[tid][2] = (int)(uint32_t)m2;
        idx6[tid][3] = (int)(uint32_t)m3;
        idx6[tid][4] = (int)(uint32_t)m4;
        idx6[tid][5] = i5;
    }
    __syncthreads();

    // ---------------- Phase 3: gather 6 rows of x_coarse, sum into LDS
    {
        const int fl   = tid >> 1;        // 2 threads per fine point
        const int half = tid & 1;         // each covers 64 of 128 dims
        const int id0 = idx6[fl][0], id1 = idx6[fl][1], id2 = idx6[fl][2];
        const int id3 = idx6[fl][3], id4 = idx6[fl][4], id5 = idx6[fl][5];
        #pragma unroll
        for (int dd = 0; dd < 16; ++dd) {
            const int d = half * 64 + dd * 4;
            const float4 x0 = *reinterpret_cast<const float4*>(xc + id0 * DIM + d);
            const float4 x1 = *reinterpret_cast<const float4*>(xc + id1 * DIM + d);
            const float4 x2 = *reinterpret_cast<const float4*>(xc + id2 * DIM + d);
            const float4 x3 = *reinterpret_cast<const float4*>(xc + id3 * DIM + d);
            const float4 x4 = *reinterpret_cast<const float4*>(xc + id4 * DIM + d);
            const float4 x5 = *reinterpret_cast<const float4*>(xc + id5 * DIM + d);
            float4 s;
            s.x = x0.x + x1.x + x2.x + x3.x + x4.x + x5.x;
            s.y = x0.y + x1.y + x2.y + x3.y + x4.y + x5.y;
            s.z = x0.z + x1.z + x2.z + x3.z + x4.z + x5.z;
            s.w = x0.w + x1.w + x2.w + x3.w + x4.w + x5.w;
            *reinterpret_cast<float4*>(&interp[fl][d]) = s;
        }
    }
    __syncthreads();

    // ---------------- Phase 4: out[f][:] = (sum/6) @ W + b   (8f x 8j per thread)
    {
        const int jq = tid & 15;          // j0 = jq*8
        const int fq = tid >> 4;          // f0 = fq*8 (0..7)
        float acc[8][8];
        #pragma unroll
        for (int i = 0; i < 8; ++i)
            #pragma unroll
            for (int j = 0; j < 8; ++j) acc[i][j] = 0.f;

        for (int d4 = 0; d4 < 32; ++d4) {
            float4 wv[4][2];
            #pragma unroll
            for (int dd = 0; dd < 4; ++dd) {
                const float4* Wr = reinterpret_cast<const float4*>(W + (d4 * 4 + dd) * DIM);
                wv[dd][0] = Wr[jq * 2 + 0];
                wv[dd][1] = Wr[jq * 2 + 1];
            }
            #pragma unroll
            for (int i = 0; i < 8; ++i) {
                const float4 s4 = *reinterpret_cast<const float4*>(&interp[fq * 8 + i][d4 * 4]);
                const float sv0 = s4.x, sv1 = s4.y, sv2 = s4.z, sv3 = s4.w;
                #define STEP(svd, dd) \
                    acc[i][0] += (svd) * wv[dd][0].x; \
                    acc[i][1] += (svd) * wv[dd][0].y; \
                    acc[i][2] += (svd) * wv[dd][0].z; \
                    acc[i][3] += (svd) * wv[dd][0].w; \
                    acc[i][4] += (svd) * wv[dd][1].x; \
                    acc[i][5] += (svd) * wv[dd][1].y; \
                    acc[i][6] += (svd) * wv[dd][1].z; \
                    acc[i][7] += (svd) * wv[dd][1].w;
                STEP(sv0, 0) STEP(sv1, 1) STEP(sv2, 2) STEP(sv3, 3)
                #undef STEP
            }
        }

        const float4 bA = reinterpret_cast<const float4*>(bias)[jq * 2 + 0];
        const float4 bB = reinterpret_cast<const float4*>(bias)[jq * 2 + 1];
        constexpr float inv6 = 1.0f / 6.0f;
        #pragma unroll
        for (int i = 0; i < 8; ++i) {
            const int fr = fbase + fq * 8 + i;
            float4 oA, oB;
            oA.x = acc[i][0] * inv6 + bA.x;
            oA.y = acc[i][1] * inv6 + bA.y;
            oA.z = acc[i][2] * inv6 + bA.z;
            oA.w = acc[i][3] * inv6 + bA.w;
            oB.x = acc[i][4] * inv6 + bB.x;
            oB.y = acc[i][5] * inv6 + bB.y;
            oB.z = acc[i][6] * inv6 + bB.z;
            oB.w = acc[i][7] * inv6 + bB.w;
            float4* orow = reinterpret_cast<float4*>(out + fr * DIM);
            orow[jq * 2 + 0] = oA;
            orow[jq * 2 + 1] = oB;
        }
    }
}

extern "C" void kernel_launch(void* const* d_in, const int* in_sizes, int n_in,
                              void* d_out, int out_size, void* d_ws, size_t ws_size,
                              hipStream_t stream) {
    const float* xc  = (const float*)d_in[0];  // x_coarse  [4000*128]
    const float* pc  = (const float*)d_in[1];  // pos_coarse[4000*3]
    const float* pf  = (const float*)d_in[2];  // pos_fine  [40000*3]
    const float* W   = (const float*)d_in[3];  // W         [128*128]
    const float* b   = (const float*)d_in[4];  // b         [128]
    float* out = (float*)d_out;                // [40000*128] f32

    upsampler_fused<<<dim3(NFINE / 64), dim3(128), 0, stream>>>(xc, pc, pf, W, b, out);
}

// Round 2
// 191.938 us; speedup vs baseline: 2.4927x; 2.4927x over previous
//
#include <hip/hip_runtime.h>
#include <cstdint>

#define NCOARSE 4000
#define NFINE   40000
#define DIM     128
#define GRES    8          // 8x8x8 cells
#define NCELLS  512
#define CELLH   0.125f

__device__ __forceinline__ uint64_t min64(uint64_t a, uint64_t b) { return a < b ? a : b; }
__device__ __forceinline__ uint64_t max64(uint64_t a, uint64_t b) { return a > b ? a : b; }

__device__ __forceinline__ int cell_coord(float x) {
    int c = (int)(x * 8.0f);
    return c < 0 ? 0 : (c > 7 ? 7 : c);
}

// ---------------- grid build kernels ----------------
__global__ __launch_bounds__(512) void k_zero(int* cnt) {
    cnt[threadIdx.x] = 0;
}

__global__ __launch_bounds__(256) void k_count(const float* __restrict__ pc, int* __restrict__ cnt) {
    int i = blockIdx.x * 256 + threadIdx.x;
    if (i < NCOARSE) {
        int cx = cell_coord(pc[i * 3 + 0]);
        int cy = cell_coord(pc[i * 3 + 1]);
        int cz = cell_coord(pc[i * 3 + 2]);
        atomicAdd(&cnt[(cz << 6) | (cy << 3) | cx], 1);
    }
}

__global__ __launch_bounds__(512) void k_scan(const int* __restrict__ cnt,
                                              int* __restrict__ cellStart,
                                              int* __restrict__ cellOfs) {
    __shared__ int s[NCELLS];
    const int t = threadIdx.x;
    const int my = cnt[t];
    s[t] = my;
    __syncthreads();
    for (int o = 1; o < NCELLS; o <<= 1) {
        int v = (t >= o) ? s[t - o] : 0;
        __syncthreads();
        s[t] += v;
        __syncthreads();
    }
    const int incl = s[t];
    const int excl = incl - my;
    cellStart[t] = excl;
    cellOfs[t]   = excl;
    if (t == NCELLS - 1) cellStart[NCELLS] = incl;   // = 4000
}

__global__ __launch_bounds__(256) void k_scatter(const float* __restrict__ pc,
                                                 int* __restrict__ cellOfs,
                                                 float4* __restrict__ pts) {
    int i = blockIdx.x * 256 + threadIdx.x;
    if (i < NCOARSE) {
        const float x = pc[i * 3 + 0];
        const float y = pc[i * 3 + 1];
        const float z = pc[i * 3 + 2];
        const int c = (cell_coord(z) << 6) | (cell_coord(y) << 3) | cell_coord(x);
        const int off = atomicAdd(&cellOfs[c], 1);
        pts[off] = make_float4(x, y, z, __int_as_float(i));
    }
}

// ---------------- fused KNN + gather + GEMM ----------------
struct GridSM {
    int    cellStart[NCELLS + 1];
    float4 pts[NCOARSE];
};
union SMU {
    GridSM g;
    float  interp[64][DIM];
};

__global__ __launch_bounds__(128) void upsampler_fused(
    const float*  __restrict__ xc,       // [4000][128]
    const float*  __restrict__ pf,       // [40000][3]
    const float*  __restrict__ W,        // [128][128]
    const float*  __restrict__ bias,     // [128]
    const int*    __restrict__ cellStartG,
    const float4* __restrict__ ptsG,
    float* __restrict__ out)             // [40000][128]
{
    __shared__ SMU sm;
    __shared__ int idx6[64][6];

    const int tid   = threadIdx.x;
    const int lane  = tid & 63;
    const int wave  = tid >> 6;
    const int fbase = blockIdx.x * 64;

    // ---- stage grid into LDS
    for (int i = tid; i < NCELLS + 1; i += 128) sm.g.cellStart[i] = cellStartG[i];
    for (int i = tid; i < NCOARSE; i += 128)    sm.g.pts[i]       = ptsG[i];
    __syncthreads();

    // ---- Phase 1: exact 7-NN per fine point; lane pair (2i,2i+1) shares one fine point
    {
        const int myPar = lane & 1;
        const int fl    = (wave << 5) | (lane >> 1);   // 0..63 local fine index
        const int f     = fbase + fl;
        const float fx = pf[f * 3 + 0];
        const float fy = pf[f * 3 + 1];
        const float fz = pf[f * 3 + 2];
        const int ix = cell_coord(fx);
        const int iy = cell_coord(fy);
        const int iz = cell_coord(fz);

        uint64_t own[7];
        #pragma unroll
        for (int r = 0; r < 7; ++r) own[r] = ~0ull;
        uint64_t mg[7];
        #pragma unroll
        for (int r = 0; r < 7; ++r) mg[r] = ~0ull;

        bool done = false;
        for (int s = 1; s <= 7 && !done; ++s) {
            // process cells with Chebyshev distance == s (== <= s on first iter)
            for (int dz = -s; dz <= s; ++dz) {
                const int cz = iz + dz;
                if ((unsigned)cz >= (unsigned)GRES) continue;
                const bool fz_face = (dz == -s) | (dz == s);
                for (int dy = -s; dy <= s; ++dy) {
                    const int cy = iy + dy;
                    if ((unsigned)cy >= (unsigned)GRES) continue;
                    const bool fy_face = (dy == -s) | (dy == s);
                    for (int dx = -s; dx <= s; ++dx) {
                        if (s > 1 && !fz_face && !fy_face && dx > -s && dx < s) continue;
                        const int cx = ix + dx;
                        if ((unsigned)cx >= (unsigned)GRES) continue;
                        const int c = (cz << 6) | (cy << 3) | cx;
                        const int beg = sm.g.cellStart[c];
                        const int end = sm.g.cellStart[c + 1];
                        // parity split of candidates between the two pair lanes
                        for (int i = beg + ((beg ^ myPar) & 1); i < end; i += 2) {
                            const float4 p = sm.g.pts[i];
                            // EXACT numpy arithmetic: no FMA, left-to-right sum
                            const float ddx = __fsub_rn(fx, p.x);
                            const float ddy = __fsub_rn(fy, p.y);
                            const float ddz = __fsub_rn(fz, p.z);
                            const float d2 = __fadd_rn(__fadd_rn(__fmul_rn(ddx, ddx),
                                                                 __fmul_rn(ddy, ddy)),
                                                       __fmul_rn(ddz, ddz));
                            const uint64_t v = ((uint64_t)__float_as_uint(d2) << 32)
                                             | (uint32_t)__float_as_uint(p.w);
                            if (v < own[6]) {
                                own[6] = min64(own[6], max64(own[5], v));
                                own[5] = min64(own[5], max64(own[4], v));
                                own[4] = min64(own[4], max64(own[3], v));
                                own[3] = min64(own[3], max64(own[2], v));
                                own[2] = min64(own[2], max64(own[1], v));
                                own[1] = min64(own[1], max64(own[0], v));
                                own[0] = min64(own[0], v);
                            }
                        }
                    }
                }
            }
            // merge own with pair partner's list via static bitonic network
            uint64_t oth[7];
            #pragma unroll
            for (int r = 0; r < 7; ++r)
                oth[r] = __shfl_xor((unsigned long long)own[r], 1);
            uint64_t v[16];
            #pragma unroll
            for (int r = 0; r < 7; ++r) v[r] = own[r];
            v[7] = ~0ull;
            v[8] = ~0ull;
            #pragma unroll
            for (int r = 0; r < 7; ++r) v[9 + r] = oth[6 - r];   // descending half
            #pragma unroll
            for (int k = 8; k >= 1; k >>= 1) {
                #pragma unroll
                for (int i = 0; i < 16; ++i) {
                    if ((i & k) == 0) {
                        const uint64_t lo = min64(v[i], v[i | k]);
                        const uint64_t hi = max64(v[i], v[i | k]);
                        v[i] = lo; v[i | k] = hi;
                    }
                }
            }
            #pragma unroll
            for (int r = 0; r < 7; ++r) mg[r] = v[r];
            // stop: true 7th distance strictly inside scanned-safe radius s*h
            const float d7 = __uint_as_float((uint32_t)(v[6] >> 32));
            const float thr = (float)s * CELLH;
            done = (d7 < thr * thr);     // NaN (sentinel) -> false -> expand
        }

        if (myPar == 0) {
            // 6th/7th sqrt tie repair (reference sorts by f32 sqrt, stable)
            int i5 = (int)(uint32_t)mg[5];
            const int i6 = (int)(uint32_t)mg[6];
            const float d5 = sqrtf(__uint_as_float((uint32_t)(mg[5] >> 32)));
            const float d6 = sqrtf(__uint_as_float((uint32_t)(mg[6] >> 32)));
            if (d5 == d6 && i6 < i5) i5 = i6;
            idx6[fl][0] = (int)(uint32_t)mg[0];
            idx6[fl][1] = (int)(uint32_t)mg[1];
            idx6[fl][2] = (int)(uint32_t)mg[2];
            idx6[fl][3] = (int)(uint32_t)mg[3];
            idx6[fl][4] = (int)(uint32_t)mg[4];
            idx6[fl][5] = i5;
        }
    }
    __syncthreads();   // idx6 ready; also all lanes done reading sm.g

    // ---- Phase 3: gather 6 rows of x_coarse, sum into LDS (reuses sm as interp)
    {
        const int fl   = tid >> 1;
        const int half = tid & 1;
        const int id0 = idx6[fl][0], id1 = idx6[fl][1], id2 = idx6[fl][2];
        const int id3 = idx6[fl][3], id4 = idx6[fl][4], id5 = idx6[fl][5];
        #pragma unroll
        for (int dd = 0; dd < 16; ++dd) {
            const int d = half * 64 + dd * 4;
            const float4 x0 = *reinterpret_cast<const float4*>(xc + id0 * DIM + d);
            const float4 x1 = *reinterpret_cast<const float4*>(xc + id1 * DIM + d);
            const float4 x2 = *reinterpret_cast<const float4*>(xc + id2 * DIM + d);
            const float4 x3 = *reinterpret_cast<const float4*>(xc + id3 * DIM + d);
            const float4 x4 = *reinterpret_cast<const float4*>(xc + id4 * DIM + d);
            const float4 x5 = *reinterpret_cast<const float4*>(xc + id5 * DIM + d);
            float4 sv;
            sv.x = x0.x + x1.x + x2.x + x3.x + x4.x + x5.x;
            sv.y = x0.y + x1.y + x2.y + x3.y + x4.y + x5.y;
            sv.z = x0.z + x1.z + x2.z + x3.z + x4.z + x5.z;
            sv.w = x0.w + x1.w + x2.w + x3.w + x4.w + x5.w;
            *reinterpret_cast<float4*>(&sm.interp[fl][d]) = sv;
        }
    }
    __syncthreads();

    // ---- Phase 4: out[f][:] = (sum/6) @ W + b   (8f x 8j register tile)
    {
        const int jq = tid & 15;
        const int fq = tid >> 4;
        float acc[8][8];
        #pragma unroll
        for (int i = 0; i < 8; ++i)
            #pragma unroll
            for (int j = 0; j < 8; ++j) acc[i][j] = 0.f;

        for (int d4 = 0; d4 < 32; ++d4) {
            float4 wv[4][2];
            #pragma unroll
            for (int dd = 0; dd < 4; ++dd) {
                const float4* Wr = reinterpret_cast<const float4*>(W + (d4 * 4 + dd) * DIM);
                wv[dd][0] = Wr[jq * 2 + 0];
                wv[dd][1] = Wr[jq * 2 + 1];
            }
            #pragma unroll
            for (int i = 0; i < 8; ++i) {
                const float4 s4 = *reinterpret_cast<const float4*>(&sm.interp[fq * 8 + i][d4 * 4]);
                const float sv0 = s4.x, sv1 = s4.y, sv2 = s4.z, sv3 = s4.w;
                #define STEP(svd, dd) \
                    acc[i][0] += (svd) * wv[dd][0].x; \
                    acc[i][1] += (svd) * wv[dd][0].y; \
                    acc[i][2] += (svd) * wv[dd][0].z; \
                    acc[i][3] += (svd) * wv[dd][0].w; \
                    acc[i][4] += (svd) * wv[dd][1].x; \
                    acc[i][5] += (svd) * wv[dd][1].y; \
                    acc[i][6] += (svd) * wv[dd][1].z; \
                    acc[i][7] += (svd) * wv[dd][1].w;
                STEP(sv0, 0) STEP(sv1, 1) STEP(sv2, 2) STEP(sv3, 3)
                #undef STEP
            }
        }

        const float4 bA = reinterpret_cast<const float4*>(bias)[jq * 2 + 0];
        const float4 bB = reinterpret_cast<const float4*>(bias)[jq * 2 + 1];
        constexpr float inv6 = 1.0f / 6.0f;
        #pragma unroll
        for (int i = 0; i < 8; ++i) {
            const int fr = fbase + fq * 8 + i;
            float4 oA, oB;
            oA.x = acc[i][0] * inv6 + bA.x;
            oA.y = acc[i][1] * inv6 + bA.y;
            oA.z = acc[i][2] * inv6 + bA.z;
            oA.w = acc[i][3] * inv6 + bA.w;
            oB.x = acc[i][4] * inv6 + bB.x;
            oB.y = acc[i][5] * inv6 + bB.y;
            oB.z = acc[i][6] * inv6 + bB.z;
            oB.w = acc[i][7] * inv6 + bB.w;
            float4* orow = reinterpret_cast<float4*>(out + fr * DIM);
            orow[jq * 2 + 0] = oA;
            orow[jq * 2 + 1] = oB;
        }
    }
}

extern "C" void kernel_launch(void* const* d_in, const int* in_sizes, int n_in,
                              void* d_out, int out_size, void* d_ws, size_t ws_size,
                              hipStream_t stream) {
    const float* xc  = (const float*)d_in[0];  // x_coarse  [4000*128]
    const float* pc  = (const float*)d_in[1];  // pos_coarse[4000*3]
    const float* pf  = (const float*)d_in[2];  // pos_fine  [40000*3]
    const float* W   = (const float*)d_in[3];  // W         [128*128]
    const float* b   = (const float*)d_in[4];  // b         [128]
    float* out = (float*)d_out;                // [40000*128] f32

    // ws layout: [0)       cellStart 513 ints  (2052 B)
    //            [2080)    cellOfs/counts 512 ints
    //            [4608)    pts 4000 float4 (64000 B)   total 68608 B
    int*    cellStartG = (int*)d_ws;
    int*    cellOfsG   = (int*)((char*)d_ws + 2080);
    float4* ptsG       = (float4*)((char*)d_ws + 4608);

    k_zero   <<<1, 512, 0, stream>>>(cellOfsG);
    k_count  <<<16, 256, 0, stream>>>(pc, cellOfsG);
    k_scan   <<<1, 512, 0, stream>>>(cellOfsG, cellStartG, cellOfsG);
    k_scatter<<<16, 256, 0, stream>>>(pc, cellOfsG, ptsG);
    upsampler_fused<<<dim3(NFINE / 64), dim3(128), 0, stream>>>(
        xc, pf, W, b, cellStartG, ptsG, out);
}

// Round 3
// 134.754 us; speedup vs baseline: 3.5505x; 1.4244x over previous
//
#include <hip/hip_runtime.h>
#include <cstdint>

#define NCOARSE 4000
#define NFINE   40000
#define DIM     128
#define GRES    8
#define CELLH   0.125f
#define SCAP    1024     // staged-candidate cap (float4)
#define ASTRIDE 132      // interp row stride in floats (conflict-free GEMM reads)

__device__ __forceinline__ uint64_t min64(uint64_t a, uint64_t b) { return a < b ? a : b; }
__device__ __forceinline__ uint64_t max64(uint64_t a, uint64_t b) { return a > b ? a : b; }
__device__ __forceinline__ int cell_coord(float x) {
    int c = (int)(x * 8.0f);
    return c < 0 ? 0 : (c > 7 ? 7 : c);
}

// ---------------- grid build + fine sort ----------------
__global__ __launch_bounds__(1024) void k_zero(int* cnt) { cnt[threadIdx.x] = 0; }

__global__ __launch_bounds__(256) void k_count(const float* __restrict__ pc,
                                               const float* __restrict__ pf,
                                               int* __restrict__ cntC, int* __restrict__ cntF) {
    int i = blockIdx.x * 256 + threadIdx.x;
    if (i < NCOARSE) {
        const int c = (cell_coord(pc[3*i+2]) << 6) | (cell_coord(pc[3*i+1]) << 3) | cell_coord(pc[3*i]);
        atomicAdd(&cntC[c], 1);
    } else {
        const int j = i - NCOARSE;
        if (j < NFINE) {
            const int c = (cell_coord(pf[3*j+2]) << 6) | (cell_coord(pf[3*j+1]) << 3) | cell_coord(pf[3*j]);
            atomicAdd(&cntF[c], 1);
        }
    }
}

__global__ __launch_bounds__(512) void k_scan(int* __restrict__ cntC, int* __restrict__ cntF,
                                              int* __restrict__ startC, int* __restrict__ startF) {
    __shared__ int s[512];
    int* cnt = blockIdx.x ? cntF : cntC;
    int* st  = blockIdx.x ? startF : startC;
    const int t = threadIdx.x;
    const int my = cnt[t];
    s[t] = my;
    __syncthreads();
    for (int o = 1; o < 512; o <<= 1) {
        int v = (t >= o) ? s[t - o] : 0;
        __syncthreads();
        s[t] += v;
        __syncthreads();
    }
    const int excl = s[t] - my;
    st[t] = excl;
    cnt[t] = excl;          // becomes the scatter offset array
    if (t == 511) st[512] = s[t];
}

__global__ __launch_bounds__(256) void k_scatter(const float* __restrict__ pc,
                                                 const float* __restrict__ pf,
                                                 int* __restrict__ ofsC, int* __restrict__ ofsF,
                                                 float4* __restrict__ pts, float4* __restrict__ srt) {
    int i = blockIdx.x * 256 + threadIdx.x;
    if (i < NCOARSE) {
        const float x = pc[3*i], y = pc[3*i+1], z = pc[3*i+2];
        const int c = (cell_coord(z) << 6) | (cell_coord(y) << 3) | cell_coord(x);
        pts[atomicAdd(&ofsC[c], 1)] = make_float4(x, y, z, __int_as_float(i));
    } else {
        const int j = i - NCOARSE;
        if (j < NFINE) {
            const float x = pf[3*j], y = pf[3*j+1], z = pf[3*j+2];
            const int c = (cell_coord(z) << 6) | (cell_coord(y) << 3) | cell_coord(x);
            srt[atomicAdd(&ofsF[c], 1)] = make_float4(x, y, z, __int_as_float(j));
        }
    }
}

// ---------------- fused KNN + gather + GEMM ----------------
struct ScanSM {
    float4 pts[SCAP];          // 16384 B (16B aligned at offset 0)
    int cellStart[513];
    int rBeg[40], rLds[40], rLen[40];
};
union SMU {
    ScanSM s;
    float  interp[64][ASTRIDE];   // 33792 B
};

__device__ __forceinline__ void pair_merge(const uint64_t own[7], uint64_t mg[7]) {
    uint64_t v[16];
    #pragma unroll
    for (int r = 0; r < 7; ++r) v[r] = own[r];
    v[7] = ~0ull; v[8] = ~0ull;
    #pragma unroll
    for (int r = 0; r < 7; ++r)
        v[9 + r] = __shfl_xor((unsigned long long)own[6 - r], 1);
    #pragma unroll
    for (int k = 8; k >= 1; k >>= 1) {
        #pragma unroll
        for (int i = 0; i < 16; ++i) {
            if ((i & k) == 0) {
                const uint64_t lo = min64(v[i], v[i | k]);
                const uint64_t hi = max64(v[i], v[i | k]);
                v[i] = lo; v[i | k] = hi;
            }
        }
    }
    #pragma unroll
    for (int r = 0; r < 7; ++r) mg[r] = v[r];
}

__device__ __forceinline__ bool done_check(uint64_t k7, float fx, float fy, float fz,
                                           int ix, int iy, int iz, int s) {
    const float d7 = __uint_as_float((uint32_t)(k7 >> 32));
    float clear = 1e30f;
    if (ix - s >= 0) clear = fminf(clear, __fsub_rn(fx, (float)(ix - s) * CELLH));
    if (ix + s <= 6) clear = fminf(clear, __fsub_rn((float)(ix + s + 1) * CELLH, fx));
    if (iy - s >= 0) clear = fminf(clear, __fsub_rn(fy, (float)(iy - s) * CELLH));
    if (iy + s <= 6) clear = fminf(clear, __fsub_rn((float)(iy + s + 1) * CELLH, fy));
    if (iz - s >= 0) clear = fminf(clear, __fsub_rn(fz, (float)(iz - s) * CELLH));
    if (iz + s <= 6) clear = fminf(clear, __fsub_rn((float)(iz + s + 1) * CELLH, fz));
    return d7 < clear * clear * 0.9999f;   // NaN sentinel -> false
}

#define INS(p) { \
    const float ddx = __fsub_rn(fx, (p).x); \
    const float ddy = __fsub_rn(fy, (p).y); \
    const float ddz = __fsub_rn(fz, (p).z); \
    const float d2  = __fadd_rn(__fadd_rn(__fmul_rn(ddx, ddx), __fmul_rn(ddy, ddy)), \
                                __fmul_rn(ddz, ddz)); \
    const uint64_t v = ((uint64_t)__float_as_uint(d2) << 32) | (uint32_t)__float_as_uint((p).w); \
    if (v < own[6]) { \
        own[6] = min64(own[6], max64(own[5], v)); \
        own[5] = min64(own[5], max64(own[4], v)); \
        own[4] = min64(own[4], max64(own[3], v)); \
        own[3] = min64(own[3], max64(own[2], v)); \
        own[2] = min64(own[2], max64(own[1], v)); \
        own[1] = min64(own[1], max64(own[0], v)); \
        own[0] = min64(own[0], v); \
    } }

__global__ __launch_bounds__(128) void upsampler_fused(
    const float*  __restrict__ xc,
    const float*  __restrict__ W,
    const float*  __restrict__ bias,
    const int*    __restrict__ cellStartG,
    const float4* __restrict__ ptsG,
    const float4* __restrict__ srtF,
    float* __restrict__ out)
{
    __shared__ SMU u;
    __shared__ int idx6[64][6];
    __shared__ int forig[64];
    __shared__ int meta[8];

    const int tid   = threadIdx.x;
    const int fl    = tid >> 1;
    const int par   = tid & 1;
    const int fbase = blockIdx.x * 64;

    for (int i = tid; i < 513; i += 128) u.s.cellStart[i] = cellStartG[i];
    if (tid < 3) meta[tid] = GRES;
    else if (tid < 6) meta[tid] = -1;
    __syncthreads();

    const float4 fp = srtF[fbase + fl];
    const float fx = fp.x, fy = fp.y, fz = fp.z;
    const int ix = cell_coord(fx), iy = cell_coord(fy), iz = cell_coord(fz);
    if (par == 0) {
        forig[fl] = __float_as_int(fp.w);
        atomicMin(&meta[0], ix); atomicMin(&meta[1], iy); atomicMin(&meta[2], iz);
        atomicMax(&meta[3], ix); atomicMax(&meta[4], iy); atomicMax(&meta[5], iz);
    }
    __syncthreads();

    const int bx0 = max(meta[0] - 1, 0), bx1 = min(meta[3] + 1, 7);
    const int by0 = max(meta[1] - 1, 0), by1 = min(meta[4] + 1, 7);
    const int bz0 = max(meta[2] - 1, 0), bz1 = min(meta[5] + 1, 7);

    if (tid == 0) {
        int nR = 0, tot = 0;
        if ((by1 - by0 + 1) * (bz1 - bz0 + 1) <= 40) {
            for (int cz = bz0; cz <= bz1 && tot <= SCAP; ++cz)
                for (int cy = by0; cy <= by1; ++cy) {
                    const int b = u.s.cellStart[(cz << 6) | (cy << 3) | bx0];
                    const int e = u.s.cellStart[((cz << 6) | (cy << 3) | bx1) + 1];
                    u.s.rBeg[nR] = b; u.s.rLds[nR] = tot; u.s.rLen[nR] = e - b;
                    tot += e - b; ++nR;
                }
        } else tot = SCAP + 1;
        meta[6] = (tot <= SCAP) ? tot : -1;
        meta[7] = nR;
    }
    __syncthreads();

    const int nStaged = meta[6];
    const bool staged = (nStaged >= 0);
    if (staged) {
        const int nR = meta[7];
        for (int r = 0; r < nR; ++r) {
            const int b = u.s.rBeg[r], o = u.s.rLds[r], L = u.s.rLen[r];
            for (int k = tid; k < L; k += 128) u.s.pts[o + k] = ptsG[b + k];
        }
    }
    __syncthreads();

    // scanned box (for shell skip + duplicate avoidance)
    const int sx0 = staged ? bx0 : max(ix - 1, 0), sx1 = staged ? bx1 : min(ix + 1, 7);
    const int sy0 = staged ? by0 : max(iy - 1, 0), sy1 = staged ? by1 : min(iy + 1, 7);
    const int sz0 = staged ? bz0 : max(iz - 1, 0), sz1 = staged ? bz1 : min(iz + 1, 7);

    uint64_t own[7];
    #pragma unroll
    for (int r = 0; r < 7; ++r) own[r] = ~0ull;

    if (staged) {
        #pragma unroll 2
        for (int i = par; i < nStaged; i += 2) { float4 p = u.s.pts[i]; INS(p) }
    } else {
        for (int cz = sz0; cz <= sz1; ++cz)
            for (int cy = sy0; cy <= sy1; ++cy) {
                const int base = (cz << 6) | (cy << 3);
                const int b = u.s.cellStart[base + sx0];
                const int e = u.s.cellStart[base + sx1 + 1];
                for (int i = b + ((b ^ par) & 1); i < e; i += 2) { float4 p = ptsG[i]; INS(p) }
            }
    }

    uint64_t mg[7];
    pair_merge(own, mg);
    bool done = done_check(mg[6], fx, fy, fz, ix, iy, iz, 1);

    for (int s = 2; s <= 7; ++s) {
        if (__all(done)) break;
        if (!done) {
            for (int dz = -s; dz <= s; ++dz) {
                const int cz = iz + dz;
                if ((unsigned)cz >= (unsigned)GRES) continue;
                const bool fz_face = (dz == -s) | (dz == s);
                for (int dy = -s; dy <= s; ++dy) {
                    const int cy = iy + dy;
                    if ((unsigned)cy >= (unsigned)GRES) continue;
                    const bool yz_face = fz_face | (dy == -s) | (dy == s);
                    for (int dx = -s; dx <= s; ++dx) {
                        if (!yz_face && dx > -s && dx < s) continue;
                        const int cx = ix + dx;
                        if ((unsigned)cx >= (unsigned)GRES) continue;
                        if (cx >= sx0 && cx <= sx1 && cy >= sy0 && cy <= sy1 &&
                            cz >= sz0 && cz <= sz1) continue;   // already scanned
                        const int cc = (cz << 6) | (cy << 3) | cx;
                        const int b = u.s.cellStart[cc], e = u.s.cellStart[cc + 1];
                        for (int i = b + ((b ^ par) & 1); i < e; i += 2) { float4 p = ptsG[i]; INS(p) }
                    }
                }
            }
            pair_merge(own, mg);
            done = done_check(mg[6], fx, fy, fz, ix, iy, iz, s);
        }
    }

    if (par == 0) {
        int i5 = (int)(uint32_t)mg[5];
        const int i6 = (int)(uint32_t)mg[6];
        const float d5 = sqrtf(__uint_as_float((uint32_t)(mg[5] >> 32)));
        const float d6 = sqrtf(__uint_as_float((uint32_t)(mg[6] >> 32)));
        if (d5 == d6 && i6 < i5) i5 = i6;
        idx6[fl][0] = (int)(uint32_t)mg[0];
        idx6[fl][1] = (int)(uint32_t)mg[1];
        idx6[fl][2] = (int)(uint32_t)mg[2];
        idx6[fl][3] = (int)(uint32_t)mg[3];
        idx6[fl][4] = (int)(uint32_t)mg[4];
        idx6[fl][5] = i5;
    }
    __syncthreads();   // scan state dead; u becomes interp

    // ---- gather 6 rows, sum into LDS (stride ASTRIDE)
    {
        const int half = par;
        const int id0 = idx6[fl][0], id1 = idx6[fl][1], id2 = idx6[fl][2];
        const int id3 = idx6[fl][3], id4 = idx6[fl][4], id5 = idx6[fl][5];
        #pragma unroll
        for (int dd = 0; dd < 16; ++dd) {
            const int d = half * 64 + dd * 4;
            const float4 x0 = *reinterpret_cast<const float4*>(xc + id0 * DIM + d);
            const float4 x1 = *reinterpret_cast<const float4*>(xc + id1 * DIM + d);
            const float4 x2 = *reinterpret_cast<const float4*>(xc + id2 * DIM + d);
            const float4 x3 = *reinterpret_cast<const float4*>(xc + id3 * DIM + d);
            const float4 x4 = *reinterpret_cast<const float4*>(xc + id4 * DIM + d);
            const float4 x5 = *reinterpret_cast<const float4*>(xc + id5 * DIM + d);
            float4 sv;
            sv.x = x0.x + x1.x + x2.x + x3.x + x4.x + x5.x;
            sv.y = x0.y + x1.y + x2.y + x3.y + x4.y + x5.y;
            sv.z = x0.z + x1.z + x2.z + x3.z + x4.z + x5.z;
            sv.w = x0.w + x1.w + x2.w + x3.w + x4.w + x5.w;
            *reinterpret_cast<float4*>(&u.interp[fl][d]) = sv;
        }
    }
    __syncthreads();

    // ---- GEMM: out[f][:] = (sum/6) @ W + b ; thread = (fq, jq), rows fq+8i
    {
        const int jq = tid & 15;
        const int fq = tid >> 4;
        float acc[8][8];
        #pragma unroll
        for (int i = 0; i < 8; ++i)
            #pragma unroll
            for (int j = 0; j < 8; ++j) acc[i][j] = 0.f;

        for (int d4 = 0; d4 < 32; ++d4) {
            float4 wv[4][2];
            #pragma unroll
            for (int dd = 0; dd < 4; ++dd) {
                const float4* Wr = reinterpret_cast<const float4*>(W + (d4 * 4 + dd) * DIM);
                wv[dd][0] = Wr[jq * 2 + 0];
                wv[dd][1] = Wr[jq * 2 + 1];
            }
            #pragma unroll
            for (int i = 0; i < 8; ++i) {
                const float4 s4 = *reinterpret_cast<const float4*>(&u.interp[fq + 8 * i][d4 * 4]);
                const float sv0 = s4.x, sv1 = s4.y, sv2 = s4.z, sv3 = s4.w;
                #define STEP(svd, dd) \
                    acc[i][0] += (svd) * wv[dd][0].x; \
                    acc[i][1] += (svd) * wv[dd][0].y; \
                    acc[i][2] += (svd) * wv[dd][0].z; \
                    acc[i][3] += (svd) * wv[dd][0].w; \
                    acc[i][4] += (svd) * wv[dd][1].x; \
                    acc[i][5] += (svd) * wv[dd][1].y; \
                    acc[i][6] += (svd) * wv[dd][1].z; \
                    acc[i][7] += (svd) * wv[dd][1].w;
                STEP(sv0, 0) STEP(sv1, 1) STEP(sv2, 2) STEP(sv3, 3)
                #undef STEP
            }
        }

        const float4 bA = reinterpret_cast<const float4*>(bias)[jq * 2 + 0];
        const float4 bB = reinterpret_cast<const float4*>(bias)[jq * 2 + 1];
        constexpr float inv6 = 1.0f / 6.0f;
        #pragma unroll
        for (int i = 0; i < 8; ++i) {
            const int fr = forig[fq + 8 * i];
            float4 oA, oB;
            oA.x = acc[i][0] * inv6 + bA.x;
            oA.y = acc[i][1] * inv6 + bA.y;
            oA.z = acc[i][2] * inv6 + bA.z;
            oA.w = acc[i][3] * inv6 + bA.w;
            oB.x = acc[i][4] * inv6 + bB.x;
            oB.y = acc[i][5] * inv6 + bB.y;
            oB.z = acc[i][6] * inv6 + bB.z;
            oB.w = acc[i][7] * inv6 + bB.w;
            float4* orow = reinterpret_cast<float4*>(out + fr * DIM);
            orow[jq * 2 + 0] = oA;
            orow[jq * 2 + 1] = oB;
        }
    }
}

extern "C" void kernel_launch(void* const* d_in, const int* in_sizes, int n_in,
                              void* d_out, int out_size, void* d_ws, size_t ws_size,
                              hipStream_t stream) {
    const float* xc = (const float*)d_in[0];
    const float* pc = (const float*)d_in[1];
    const float* pf = (const float*)d_in[2];
    const float* W  = (const float*)d_in[3];
    const float* b  = (const float*)d_in[4];
    float* out = (float*)d_out;

    // ws layout (bytes):
    //   0      cntC/ofsC   512 ints
    //   2048   cntF/ofsF   512 ints
    //   4096   startC      513 ints (pad to 2064)
    //   6160   startF      513 ints (pad to 8224)
    //   8224   pts         4000 float4  (64000)
    //   72224  srtF        40000 float4 (640000)  -> total 712224
    int*    cntC   = (int*)d_ws;
    int*    cntF   = (int*)((char*)d_ws + 2048);
    int*    startC = (int*)((char*)d_ws + 4096);
    int*    startF = (int*)((char*)d_ws + 6160);
    float4* pts    = (float4*)((char*)d_ws + 8224);
    float4* srt    = (float4*)((char*)d_ws + 72224);

    k_zero   <<<1, 1024, 0, stream>>>(cntC);      // zeros cntC and cntF (contiguous)
    k_count  <<<172, 256, 0, stream>>>(pc, pf, cntC, cntF);
    k_scan   <<<2, 512, 0, stream>>>(cntC, cntF, startC, startF);
    k_scatter<<<172, 256, 0, stream>>>(pc, pf, cntC, cntF, pts, srt);
    upsampler_fused<<<dim3(NFINE / 64), dim3(128), 0, stream>>>(
        xc, W, b, startC, pts, srt, out);
}

// Round 4
// 99.781 us; speedup vs baseline: 4.7950x; 1.3505x over previous
//
#include <hip/hip_runtime.h>
#include <cstdint>

#define NCOARSE 4000
#define NFINE   40000
#define DIM     128
#define GRES    8
#define CELLH   0.125f
#define SCAP    768      // staged-candidate cap (float4)
#define ASTRIDE 132      // interp row stride in floats
#define PPB     32       // fine points per block (4 lanes each, 128 threads)

__device__ __forceinline__ uint64_t min64(uint64_t a, uint64_t b) { return a < b ? a : b; }
__device__ __forceinline__ uint64_t max64(uint64_t a, uint64_t b) { return a > b ? a : b; }
__device__ __forceinline__ int cell_coord(float x) {
    int c = (int)(x * 8.0f);
    return c < 0 ? 0 : (c > 7 ? 7 : c);
}

// ---------------- grid build + fine sort ----------------
__global__ __launch_bounds__(256) void k_count(const float* __restrict__ pc,
                                               const float* __restrict__ pf,
                                               int* __restrict__ cntC, int* __restrict__ cntF) {
    int i = blockIdx.x * 256 + threadIdx.x;
    if (i < NCOARSE) {
        const int c = (cell_coord(pc[3*i+2]) << 6) | (cell_coord(pc[3*i+1]) << 3) | cell_coord(pc[3*i]);
        atomicAdd(&cntC[c], 1);
    } else {
        const int j = i - NCOARSE;
        if (j < NFINE) {
            const int c = (cell_coord(pf[3*j+2]) << 6) | (cell_coord(pf[3*j+1]) << 3) | cell_coord(pf[3*j]);
            atomicAdd(&cntF[c], 1);
        }
    }
}

__global__ __launch_bounds__(512) void k_scan(int* __restrict__ cntC, int* __restrict__ cntF,
                                              int* __restrict__ startC, int* __restrict__ startF) {
    __shared__ int s[512];
    int* cnt = blockIdx.x ? cntF : cntC;
    int* st  = blockIdx.x ? startF : startC;
    const int t = threadIdx.x;
    const int my = cnt[t];
    s[t] = my;
    __syncthreads();
    for (int o = 1; o < 512; o <<= 1) {
        int v = (t >= o) ? s[t - o] : 0;
        __syncthreads();
        s[t] += v;
        __syncthreads();
    }
    const int excl = s[t] - my;
    st[t] = excl;
    cnt[t] = excl;          // becomes the scatter offset array
    if (t == 511) st[512] = s[t];
}

__global__ __launch_bounds__(256) void k_scatter(const float* __restrict__ pc,
                                                 const float* __restrict__ pf,
                                                 int* __restrict__ ofsC, int* __restrict__ ofsF,
                                                 float4* __restrict__ pts, float4* __restrict__ srt) {
    int i = blockIdx.x * 256 + threadIdx.x;
    if (i < NCOARSE) {
        const float x = pc[3*i], y = pc[3*i+1], z = pc[3*i+2];
        const int c = (cell_coord(z) << 6) | (cell_coord(y) << 3) | cell_coord(x);
        pts[atomicAdd(&ofsC[c], 1)] = make_float4(x, y, z, __int_as_float(i));
    } else {
        const int j = i - NCOARSE;
        if (j < NFINE) {
            const float x = pf[3*j], y = pf[3*j+1], z = pf[3*j+2];
            const int c = (cell_coord(z) << 6) | (cell_coord(y) << 3) | cell_coord(x);
            srt[atomicAdd(&ofsF[c], 1)] = make_float4(x, y, z, __int_as_float(j));
        }
    }
}

// ---------------- fused KNN + gather + GEMM ----------------
struct ScanSM {
    float4 pts[SCAP];          // 12288 B
    int cellStart[513];
    int rBeg[40], rLds[40], rLen[40];
};
union SMU {
    ScanSM s;
    float  interp[PPB][ASTRIDE];   // 16896 B
};

// merge this lane's sorted 7-list with lane^mask's (both sorted asc) -> sorted top-7
__device__ __forceinline__ void merge_with(uint64_t w[7], int mask) {
    uint64_t v[16];
    #pragma unroll
    for (int r = 0; r < 7; ++r) v[r] = w[r];
    v[7] = ~0ull; v[8] = ~0ull;
    #pragma unroll
    for (int r = 0; r < 7; ++r)
        v[9 + r] = __shfl_xor((unsigned long long)w[6 - r], mask);
    #pragma unroll
    for (int k = 8; k >= 1; k >>= 1) {
        #pragma unroll
        for (int i = 0; i < 16; ++i) {
            if ((i & k) == 0) {
                const uint64_t lo = min64(v[i], v[i | k]);
                v[i | k] = max64(v[i], v[i | k]);
                v[i] = lo;
            }
        }
    }
    #pragma unroll
    for (int r = 0; r < 7; ++r) w[r] = v[r];
}

__device__ __forceinline__ bool done_check(uint64_t k7, float fx, float fy, float fz,
                                           int ix, int iy, int iz, int s) {
    const float d7 = __uint_as_float((uint32_t)(k7 >> 32));
    float clear = 1e30f;
    if (ix - s >= 0) clear = fminf(clear, __fsub_rn(fx, (float)(ix - s) * CELLH));
    if (ix + s <= 6) clear = fminf(clear, __fsub_rn((float)(ix + s + 1) * CELLH, fx));
    if (iy - s >= 0) clear = fminf(clear, __fsub_rn(fy, (float)(iy - s) * CELLH));
    if (iy + s <= 6) clear = fminf(clear, __fsub_rn((float)(iy + s + 1) * CELLH, fy));
    if (iz - s >= 0) clear = fminf(clear, __fsub_rn(fz, (float)(iz - s) * CELLH));
    if (iz + s <= 6) clear = fminf(clear, __fsub_rn((float)(iz + s + 1) * CELLH, fz));
    return d7 < clear * clear * 0.9999f;   // NaN sentinel -> false
}

#define INS(p) { \
    const float ddx = __fsub_rn(fx, (p).x); \
    const float ddy = __fsub_rn(fy, (p).y); \
    const float ddz = __fsub_rn(fz, (p).z); \
    const float d2  = __fadd_rn(__fadd_rn(__fmul_rn(ddx, ddx), __fmul_rn(ddy, ddy)), \
                                __fmul_rn(ddz, ddz)); \
    const uint64_t v = ((uint64_t)__float_as_uint(d2) << 32) | (uint32_t)__float_as_uint((p).w); \
    if (v < own[6]) { \
        own[6] = min64(own[6], max64(own[5], v)); \
        own[5] = min64(own[5], max64(own[4], v)); \
        own[4] = min64(own[4], max64(own[3], v)); \
        own[3] = min64(own[3], max64(own[2], v)); \
        own[2] = min64(own[2], max64(own[1], v)); \
        own[1] = min64(own[1], max64(own[0], v)); \
        own[0] = min64(own[0], v); \
    } }

__global__ __launch_bounds__(128) void upsampler_fused(
    const float*  __restrict__ xc,
    const float*  __restrict__ W,
    const float*  __restrict__ bias,
    const int*    __restrict__ cellStartG,
    const float4* __restrict__ ptsG,
    const float4* __restrict__ srtF,
    float* __restrict__ out)
{
    __shared__ SMU u;
    __shared__ int idx6[PPB][6];
    __shared__ int forig[PPB];
    __shared__ int meta[8];

    const int tid   = threadIdx.x;
    const int fl    = tid >> 2;        // 0..31 local fine point
    const int par   = tid & 3;         // lane within point-quad
    const int fbase = blockIdx.x * PPB;

    for (int i = tid; i < 513; i += 128) u.s.cellStart[i] = cellStartG[i];
    if (tid < 3) meta[tid] = GRES;
    else if (tid < 6) meta[tid] = -1;
    __syncthreads();

    const float4 fp = srtF[fbase + fl];
    const float fx = fp.x, fy = fp.y, fz = fp.z;
    const int ix = cell_coord(fx), iy = cell_coord(fy), iz = cell_coord(fz);
    if (par == 0) {
        forig[fl] = __float_as_int(fp.w);
        atomicMin(&meta[0], ix); atomicMin(&meta[1], iy); atomicMin(&meta[2], iz);
        atomicMax(&meta[3], ix); atomicMax(&meta[4], iy); atomicMax(&meta[5], iz);
    }
    __syncthreads();

    const int bx0 = max(meta[0] - 1, 0), bx1 = min(meta[3] + 1, 7);
    const int by0 = max(meta[1] - 1, 0), by1 = min(meta[4] + 1, 7);
    const int bz0 = max(meta[2] - 1, 0), bz1 = min(meta[5] + 1, 7);

    if (tid == 0) {
        int nR = 0, tot = 0;
        if ((by1 - by0 + 1) * (bz1 - bz0 + 1) <= 40) {
            for (int cz = bz0; cz <= bz1 && tot <= SCAP; ++cz)
                for (int cy = by0; cy <= by1; ++cy) {
                    const int b = u.s.cellStart[(cz << 6) | (cy << 3) | bx0];
                    const int e = u.s.cellStart[((cz << 6) | (cy << 3) | bx1) + 1];
                    u.s.rBeg[nR] = b; u.s.rLds[nR] = tot; u.s.rLen[nR] = e - b;
                    tot += e - b; ++nR;
                }
        } else tot = SCAP + 1;
        meta[6] = (tot <= SCAP) ? tot : -1;
        meta[7] = nR;
    }
    __syncthreads();

    const int nStaged = meta[6];
    const bool staged = (nStaged >= 0);
    if (staged) {
        const int nR = meta[7];
        for (int r = 0; r < nR; ++r) {
            const int b = u.s.rBeg[r], o = u.s.rLds[r], L = u.s.rLen[r];
            for (int k = tid; k < L; k += 128) u.s.pts[o + k] = ptsG[b + k];
        }
    }
    __syncthreads();

    // scanned box (for shell skip + duplicate avoidance)
    const int sx0 = staged ? bx0 : max(ix - 1, 0), sx1 = staged ? bx1 : min(ix + 1, 7);
    const int sy0 = staged ? by0 : max(iy - 1, 0), sy1 = staged ? by1 : min(iy + 1, 7);
    const int sz0 = staged ? bz0 : max(iz - 1, 0), sz1 = staged ? bz1 : min(iz + 1, 7);

    uint64_t own[7];
    #pragma unroll
    for (int r = 0; r < 7; ++r) own[r] = ~0ull;

    if (staged) {
        #pragma unroll 4
        for (int i = par; i < nStaged; i += 4) { float4 p = u.s.pts[i]; INS(p) }
    } else {
        for (int cz = sz0; cz <= sz1; ++cz)
            for (int cy = sy0; cy <= sy1; ++cy) {
                const int base = (cz << 6) | (cy << 3);
                const int b = u.s.cellStart[base + sx0];
                const int e = u.s.cellStart[base + sx1 + 1];
                for (int i = b + ((par - b) & 3); i < e; i += 4) { float4 p = ptsG[i]; INS(p) }
            }
    }

    uint64_t mg[7];
    #pragma unroll
    for (int r = 0; r < 7; ++r) mg[r] = own[r];
    merge_with(mg, 1);
    merge_with(mg, 2);
    bool done = done_check(mg[6], fx, fy, fz, ix, iy, iz, 1);

    for (int s = 2; s <= 7; ++s) {
        if (__all(done)) break;
        if (!done) {
            for (int dz = -s; dz <= s; ++dz) {
                const int cz = iz + dz;
                if ((unsigned)cz >= (unsigned)GRES) continue;
                const bool fz_face = (dz == -s) | (dz == s);
                for (int dy = -s; dy <= s; ++dy) {
                    const int cy = iy + dy;
                    if ((unsigned)cy >= (unsigned)GRES) continue;
                    const bool yz_face = fz_face | (dy == -s) | (dy == s);
                    for (int dx = -s; dx <= s; ++dx) {
                        if (!yz_face && dx > -s && dx < s) continue;
                        const int cx = ix + dx;
                        if ((unsigned)cx >= (unsigned)GRES) continue;
                        if (cx >= sx0 && cx <= sx1 && cy >= sy0 && cy <= sy1 &&
                            cz >= sz0 && cz <= sz1) continue;   // already scanned
                        const int cc = (cz << 6) | (cy << 3) | cx;
                        const int b = u.s.cellStart[cc], e = u.s.cellStart[cc + 1];
                        for (int i = b + ((par - b) & 3); i < e; i += 4) { float4 p = ptsG[i]; INS(p) }
                    }
                }
            }
            #pragma unroll
            for (int r = 0; r < 7; ++r) mg[r] = own[r];
            merge_with(mg, 1);
            merge_with(mg, 2);
            done = done_check(mg[6], fx, fy, fz, ix, iy, iz, s);
        }
    }

    if (par == 0) {
        int i5 = (int)(uint32_t)mg[5];
        const int i6 = (int)(uint32_t)mg[6];
        const float d5 = sqrtf(__uint_as_float((uint32_t)(mg[5] >> 32)));
        const float d6 = sqrtf(__uint_as_float((uint32_t)(mg[6] >> 32)));
        if (d5 == d6 && i6 < i5) i5 = i6;
        idx6[fl][0] = (int)(uint32_t)mg[0];
        idx6[fl][1] = (int)(uint32_t)mg[1];
        idx6[fl][2] = (int)(uint32_t)mg[2];
        idx6[fl][3] = (int)(uint32_t)mg[3];
        idx6[fl][4] = (int)(uint32_t)mg[4];
        idx6[fl][5] = i5;
    }
    __syncthreads();   // scan state dead; u becomes interp

    // ---- gather 6 rows, sum into LDS; lane par covers dims {dd*16 + par*4} (bank-spread)
    {
        const int id0 = idx6[fl][0], id1 = idx6[fl][1], id2 = idx6[fl][2];
        const int id3 = idx6[fl][3], id4 = idx6[fl][4], id5 = idx6[fl][5];
        #pragma unroll
        for (int dd = 0; dd < 8; ++dd) {
            const int d = dd * 16 + par * 4;
            const float4 x0 = *reinterpret_cast<const float4*>(xc + id0 * DIM + d);
            const float4 x1 = *reinterpret_cast<const float4*>(xc + id1 * DIM + d);
            const float4 x2 = *reinterpret_cast<const float4*>(xc + id2 * DIM + d);
            const float4 x3 = *reinterpret_cast<const float4*>(xc + id3 * DIM + d);
            const float4 x4 = *reinterpret_cast<const float4*>(xc + id4 * DIM + d);
            const float4 x5 = *reinterpret_cast<const float4*>(xc + id5 * DIM + d);
            float4 sv;
            sv.x = x0.x + x1.x + x2.x + x3.x + x4.x + x5.x;
            sv.y = x0.y + x1.y + x2.y + x3.y + x4.y + x5.y;
            sv.z = x0.z + x1.z + x2.z + x3.z + x4.z + x5.z;
            sv.w = x0.w + x1.w + x2.w + x3.w + x4.w + x5.w;
            *reinterpret_cast<float4*>(&u.interp[fl][d]) = sv;
        }
    }
    __syncthreads();

    // ---- GEMM: out[f][:] = (sum/6) @ W + b ; thread=(rq,jq): rows rq+4i, cols jq*4..+3
    {
        const int jq = tid & 31;
        const int rq = tid >> 5;
        float acc[8][4];
        #pragma unroll
        for (int i = 0; i < 8; ++i)
            #pragma unroll
            for (int j = 0; j < 4; ++j) acc[i][j] = 0.f;

        for (int d4 = 0; d4 < 32; ++d4) {
            float4 wv[4];
            #pragma unroll
            for (int dd = 0; dd < 4; ++dd)
                wv[dd] = *reinterpret_cast<const float4*>(W + (d4 * 4 + dd) * DIM + jq * 4);
            #pragma unroll
            for (int i = 0; i < 8; ++i) {
                const float4 a4 = *reinterpret_cast<const float4*>(&u.interp[rq + 4 * i][d4 * 4]);
                #define GSTEP(av, dd) \
                    acc[i][0] += (av) * wv[dd].x; \
                    acc[i][1] += (av) * wv[dd].y; \
                    acc[i][2] += (av) * wv[dd].z; \
                    acc[i][3] += (av) * wv[dd].w;
                GSTEP(a4.x, 0) GSTEP(a4.y, 1) GSTEP(a4.z, 2) GSTEP(a4.w, 3)
                #undef GSTEP
            }
        }

        const float4 b4 = *reinterpret_cast<const float4*>(bias + jq * 4);
        constexpr float inv6 = 1.0f / 6.0f;
        #pragma unroll
        for (int i = 0; i < 8; ++i) {
            const int fr = forig[rq + 4 * i];
            float4 o;
            o.x = acc[i][0] * inv6 + b4.x;
            o.y = acc[i][1] * inv6 + b4.y;
            o.z = acc[i][2] * inv6 + b4.z;
            o.w = acc[i][3] * inv6 + b4.w;
            *reinterpret_cast<float4*>(out + fr * DIM + jq * 4) = o;
        }
    }
}

extern "C" void kernel_launch(void* const* d_in, const int* in_sizes, int n_in,
                              void* d_out, int out_size, void* d_ws, size_t ws_size,
                              hipStream_t stream) {
    const float* xc = (const float*)d_in[0];
    const float* pc = (const float*)d_in[1];
    const float* pf = (const float*)d_in[2];
    const float* W  = (const float*)d_in[3];
    const float* b  = (const float*)d_in[4];
    float* out = (float*)d_out;

    // ws layout (bytes):
    //   0      cntC/ofsC   512 ints
    //   2048   cntF/ofsF   512 ints
    //   4096   startC      513 ints (pad to 2064)
    //   6160   startF      513 ints (pad to 8224)
    //   8224   pts         4000 float4  (64000)
    //   72224  srtF        40000 float4 (640000)  -> total 712224
    int*    cntC   = (int*)d_ws;
    int*    cntF   = (int*)((char*)d_ws + 2048);
    int*    startC = (int*)((char*)d_ws + 4096);
    int*    startF = (int*)((char*)d_ws + 6160);
    float4* pts    = (float4*)((char*)d_ws + 8224);
    float4* srt    = (float4*)((char*)d_ws + 72224);

    hipMemsetAsync(d_ws, 0, 4096, stream);        // zero cntC + cntF
    k_count  <<<172, 256, 0, stream>>>(pc, pf, cntC, cntF);
    k_scan   <<<2, 512, 0, stream>>>(cntC, cntF, startC, startF);
    k_scatter<<<172, 256, 0, stream>>>(pc, pf, cntC, cntF, pts, srt);
    upsampler_fused<<<dim3(NFINE / PPB), dim3(128), 0, stream>>>(
        xc, W, b, startC, pts, srt, out);
}

// Round 6
// 94.494 us; speedup vs baseline: 5.0633x; 1.0559x over previous
//
#include <hip/hip_runtime.h>
#include <cstdint>

#define NCOARSE 4000
#define NFINE   40000
#define DIM     128
#define GRES    8
#define CELLH   0.125f
#define SCAP    768      // staged-candidate cap (float4)
#define ASTRIDE 132      // interp row stride in floats
#define PPB     32       // fine points per block
#define NTHR    256      // 8 lanes per fine point
#define NBLK    (NFINE / PPB)   // 1250

__device__ __forceinline__ uint64_t min64(uint64_t a, uint64_t b) { return a < b ? a : b; }
__device__ __forceinline__ uint64_t max64(uint64_t a, uint64_t b) { return a > b ? a : b; }
__device__ __forceinline__ int cell_coord(float x) {
    int c = (int)(x * 8.0f);
    return c < 0 ? 0 : (c > 7 ? 7 : c);
}

// ---------------- grid build + fine sort (proven round-4 pipeline) ----------------
__global__ __launch_bounds__(256) void k_count(const float* __restrict__ pc,
                                               const float* __restrict__ pf,
                                               int* __restrict__ cntC, int* __restrict__ cntF) {
    int i = blockIdx.x * 256 + threadIdx.x;
    if (i < NCOARSE) {
        const int c = (cell_coord(pc[3*i+2]) << 6) | (cell_coord(pc[3*i+1]) << 3) | cell_coord(pc[3*i]);
        atomicAdd(&cntC[c], 1);
    } else {
        const int j = i - NCOARSE;
        if (j < NFINE) {
            const int c = (cell_coord(pf[3*j+2]) << 6) | (cell_coord(pf[3*j+1]) << 3) | cell_coord(pf[3*j]);
            atomicAdd(&cntF[c], 1);
        }
    }
}

__global__ __launch_bounds__(512) void k_scan(int* __restrict__ cntC, int* __restrict__ cntF,
                                              int* __restrict__ startC, int* __restrict__ startF) {
    __shared__ int s[512];
    int* cnt = blockIdx.x ? cntF : cntC;
    int* st  = blockIdx.x ? startF : startC;
    const int t = threadIdx.x;
    const int my = cnt[t];
    s[t] = my;
    __syncthreads();
    for (int o = 1; o < 512; o <<= 1) {
        int v = (t >= o) ? s[t - o] : 0;
        __syncthreads();
        s[t] += v;
        __syncthreads();
    }
    const int excl = s[t] - my;
    st[t] = excl;
    cnt[t] = excl;          // becomes the scatter offset array
    if (t == 511) st[512] = s[t];
}

__global__ __launch_bounds__(256) void k_scatter(const float* __restrict__ pc,
                                                 const float* __restrict__ pf,
                                                 int* __restrict__ ofsC, int* __restrict__ ofsF,
                                                 float4* __restrict__ pts, float4* __restrict__ srt) {
    int i = blockIdx.x * 256 + threadIdx.x;
    if (i < NCOARSE) {
        const float x = pc[3*i], y = pc[3*i+1], z = pc[3*i+2];
        const int c = (cell_coord(z) << 6) | (cell_coord(y) << 3) | cell_coord(x);
        pts[atomicAdd(&ofsC[c], 1)] = make_float4(x, y, z, __int_as_float(i));
    } else {
        const int j = i - NCOARSE;
        if (j < NFINE) {
            const float x = pf[3*j], y = pf[3*j+1], z = pf[3*j+2];
            const int c = (cell_coord(z) << 6) | (cell_coord(y) << 3) | cell_coord(x);
            srt[atomicAdd(&ofsF[c], 1)] = make_float4(x, y, z, __int_as_float(j));
        }
    }
}

// ---------------- fused KNN + gather + GEMM ----------------
struct ScanSM {
    float4 pts[SCAP];          // 12288 B
    int cellStart[513];
    int rBeg[40], rLds[40];
};
union SMU {
    ScanSM s;
    float  interp[PPB][ASTRIDE];   // 16896 B
};

// merge this lane's sorted 7-list with lane^mask's -> sorted top-7 of union
__device__ __forceinline__ void merge_with(uint64_t w[7], int mask) {
    uint64_t v[16];
    #pragma unroll
    for (int r = 0; r < 7; ++r) v[r] = w[r];
    v[7] = ~0ull; v[8] = ~0ull;
    #pragma unroll
    for (int r = 0; r < 7; ++r)
        v[9 + r] = __shfl_xor((unsigned long long)w[6 - r], mask);
    #pragma unroll
    for (int k = 8; k >= 1; k >>= 1) {
        #pragma unroll
        for (int i = 0; i < 16; ++i) {
            if ((i & k) == 0) {
                const uint64_t lo = min64(v[i], v[i | k]);
                v[i | k] = max64(v[i], v[i | k]);
                v[i] = lo;
            }
        }
    }
    #pragma unroll
    for (int r = 0; r < 7; ++r) w[r] = v[r];
}

__device__ __forceinline__ bool done_check(uint64_t k7, float fx, float fy, float fz,
                                           int ix, int iy, int iz, int s) {
    const float d7 = __uint_as_float((uint32_t)(k7 >> 32));
    float clear = 1e30f;
    if (ix - s >= 0) clear = fminf(clear, __fsub_rn(fx, (float)(ix - s) * CELLH));
    if (ix + s <= 6) clear = fminf(clear, __fsub_rn((float)(ix + s + 1) * CELLH, fx));
    if (iy - s >= 0) clear = fminf(clear, __fsub_rn(fy, (float)(iy - s) * CELLH));
    if (iy + s <= 6) clear = fminf(clear, __fsub_rn((float)(iy + s + 1) * CELLH, fy));
    if (iz - s >= 0) clear = fminf(clear, __fsub_rn(fz, (float)(iz - s) * CELLH));
    if (iz + s <= 6) clear = fminf(clear, __fsub_rn((float)(iz + s + 1) * CELLH, fz));
    return d7 < clear * clear * 0.9999f;   // NaN sentinel -> false
}

#define INS(p) { \
    const float ddx = __fsub_rn(fx, (p).x); \
    const float ddy = __fsub_rn(fy, (p).y); \
    const float ddz = __fsub_rn(fz, (p).z); \
    const float d2  = __fadd_rn(__fadd_rn(__fmul_rn(ddx, ddx), __fmul_rn(ddy, ddy)), \
                                __fmul_rn(ddz, ddz)); \
    const uint64_t v = ((uint64_t)__float_as_uint(d2) << 32) | (uint32_t)__float_as_uint((p).w); \
    if (v < own[6]) { \
        own[6] = min64(own[6], max64(own[5], v)); \
        own[5] = min64(own[5], max64(own[4], v)); \
        own[4] = min64(own[4], max64(own[3], v)); \
        own[3] = min64(own[3], max64(own[2], v)); \
        own[2] = min64(own[2], max64(own[1], v)); \
        own[1] = min64(own[1], max64(own[0], v)); \
        own[0] = min64(own[0], v); \
    } }

__global__ __launch_bounds__(NTHR) void upsampler_fused(
    const float*  __restrict__ xc,
    const float*  __restrict__ W,
    const float*  __restrict__ bias,
    const int*    __restrict__ cellStartG,
    const float4* __restrict__ ptsG,
    const float4* __restrict__ srtF,
    float* __restrict__ out)
{
    __shared__ SMU u;
    __shared__ int idx6[PPB][6];
    __shared__ int forig[PPB];
    __shared__ int meta[8];

    const int tid   = threadIdx.x;
    const int fl    = tid >> 3;        // 0..31 local fine point
    const int par   = tid & 7;         // lane within point-octet
    const int fbase = blockIdx.x * PPB;

    for (int i = tid; i < 513; i += NTHR) u.s.cellStart[i] = cellStartG[i];
    if (tid < 3) meta[tid] = GRES;
    else if (tid < 6) meta[tid] = -1;
    __syncthreads();

    const float4 fp = srtF[fbase + fl];
    const float fx = fp.x, fy = fp.y, fz = fp.z;
    const int ix = cell_coord(fx), iy = cell_coord(fy), iz = cell_coord(fz);
    if (par == 0) {
        forig[fl] = __float_as_int(fp.w);
        atomicMin(&meta[0], ix); atomicMin(&meta[1], iy); atomicMin(&meta[2], iz);
        atomicMax(&meta[3], ix); atomicMax(&meta[4], iy); atomicMax(&meta[5], iz);
    }
    __syncthreads();

    const int bx0 = max(meta[0] - 1, 0), bx1 = min(meta[3] + 1, 7);
    const int by0 = max(meta[1] - 1, 0), by1 = min(meta[4] + 1, 7);
    const int bz0 = max(meta[2] - 1, 0), bz1 = min(meta[5] + 1, 7);
    const int ny = by1 - by0 + 1, nz = bz1 - bz0 + 1;
    const int nRows = ny * nz;

    // row table + prefix by first wave (shuffle scan)
    if (tid < 64) {
        int len = 0, bg = 0;
        const bool valid = (tid < nRows) && (nRows <= 40);
        if (valid) {
            const int cy = by0 + tid % ny;
            const int cz = bz0 + tid / ny;
            bg  = u.s.cellStart[(cz << 6) | (cy << 3) | bx0];
            len = u.s.cellStart[((cz << 6) | (cy << 3) | bx1) + 1] - bg;
        }
        int x = len;
        #pragma unroll
        for (int o = 1; o < 64; o <<= 1) {
            const int v = __shfl_up(x, o);
            if (tid >= o) x += v;
        }
        if (valid) { u.s.rBeg[tid] = bg; u.s.rLds[tid] = x - len; }
        if (tid == 63) meta[6] = (nRows <= 40 && x <= SCAP) ? x : -1;
        if (tid == 0)  meta[7] = nRows;
    }
    __syncthreads();

    const int nStaged = meta[6];
    const bool staged = (nStaged >= 0);
    if (staged) {
        const int nR = meta[7];
        for (int g = tid; g < nStaged; g += NTHR) {
            int lo = 0, hi = nR - 1;
            while (lo < hi) { const int mid = (lo + hi + 1) >> 1; if (u.s.rLds[mid] <= g) lo = mid; else hi = mid - 1; }
            u.s.pts[g] = ptsG[u.s.rBeg[lo] + (g - u.s.rLds[lo])];
        }
    }
    __syncthreads();

    const int sx0 = staged ? bx0 : max(ix - 1, 0), sx1 = staged ? bx1 : min(ix + 1, 7);
    const int sy0 = staged ? by0 : max(iy - 1, 0), sy1 = staged ? by1 : min(iy + 1, 7);
    const int sz0 = staged ? bz0 : max(iz - 1, 0), sz1 = staged ? bz1 : min(iz + 1, 7);

    uint64_t own[7];
    #pragma unroll
    for (int r = 0; r < 7; ++r) own[r] = ~0ull;

    if (staged) {
        #pragma unroll 4
        for (int i = par; i < nStaged; i += 8) { float4 p = u.s.pts[i]; INS(p) }
    } else {
        for (int cz = sz0; cz <= sz1; ++cz)
            for (int cy = sy0; cy <= sy1; ++cy) {
                const int base = (cz << 6) | (cy << 3);
                const int b = u.s.cellStart[base + sx0];
                const int e = u.s.cellStart[base + sx1 + 1];
                for (int i = b + ((par - b) & 7); i < e; i += 8) { float4 p = ptsG[i]; INS(p) }
            }
    }

    uint64_t mg[7];
    #pragma unroll
    for (int r = 0; r < 7; ++r) mg[r] = own[r];
    merge_with(mg, 1); merge_with(mg, 2); merge_with(mg, 4);
    bool done = done_check(mg[6], fx, fy, fz, ix, iy, iz, 1);

    for (int s = 2; s <= 7; ++s) {
        if (__all(done)) break;
        if (!done) {
            for (int dz = -s; dz <= s; ++dz) {
                const int cz = iz + dz;
                if ((unsigned)cz >= (unsigned)GRES) continue;
                const bool fz_face = (dz == -s) | (dz == s);
                for (int dy = -s; dy <= s; ++dy) {
                    const int cy = iy + dy;
                    if ((unsigned)cy >= (unsigned)GRES) continue;
                    const bool yz_face = fz_face | (dy == -s) | (dy == s);
                    for (int dx = -s; dx <= s; ++dx) {
                        if (!yz_face && dx > -s && dx < s) continue;
                        const int cx = ix + dx;
                        if ((unsigned)cx >= (unsigned)GRES) continue;
                        if (cx >= sx0 && cx <= sx1 && cy >= sy0 && cy <= sy1 &&
                            cz >= sz0 && cz <= sz1) continue;
                        const int cc = (cz << 6) | (cy << 3) | cx;
                        const int b = u.s.cellStart[cc], e = u.s.cellStart[cc + 1];
                        for (int i = b + ((par - b) & 7); i < e; i += 8) { float4 p = ptsG[i]; INS(p) }
                    }
                }
            }
            #pragma unroll
            for (int r = 0; r < 7; ++r) mg[r] = own[r];
            merge_with(mg, 1); merge_with(mg, 2); merge_with(mg, 4);
            done = done_check(mg[6], fx, fy, fz, ix, iy, iz, s);
        }
    }

    if (par == 0) {
        int i5 = (int)(uint32_t)mg[5];
        const int i6 = (int)(uint32_t)mg[6];
        const float d5 = sqrtf(__uint_as_float((uint32_t)(mg[5] >> 32)));
        const float d6 = sqrtf(__uint_as_float((uint32_t)(mg[6] >> 32)));
        if (d5 == d6 && i6 < i5) i5 = i6;
        idx6[fl][0] = (int)(uint32_t)mg[0];
        idx6[fl][1] = (int)(uint32_t)mg[1];
        idx6[fl][2] = (int)(uint32_t)mg[2];
        idx6[fl][3] = (int)(uint32_t)mg[3];
        idx6[fl][4] = (int)(uint32_t)mg[4];
        idx6[fl][5] = i5;
    }
    __syncthreads();   // all scanning done; u becomes interp

    // ---- gather 6 rows, sum into LDS; lane par covers 16 dims
    {
        const int id0 = idx6[fl][0], id1 = idx6[fl][1], id2 = idx6[fl][2];
        const int id3 = idx6[fl][3], id4 = idx6[fl][4], id5 = idx6[fl][5];
        #pragma unroll
        for (int k = 0; k < 4; ++k) {
            const int d = par * 16 + k * 4;
            const float4 x0 = *reinterpret_cast<const float4*>(xc + id0 * DIM + d);
            const float4 x1 = *reinterpret_cast<const float4*>(xc + id1 * DIM + d);
            const float4 x2 = *reinterpret_cast<const float4*>(xc + id2 * DIM + d);
            const float4 x3 = *reinterpret_cast<const float4*>(xc + id3 * DIM + d);
            const float4 x4 = *reinterpret_cast<const float4*>(xc + id4 * DIM + d);
            const float4 x5 = *reinterpret_cast<const float4*>(xc + id5 * DIM + d);
            float4 sv;
            sv.x = x0.x + x1.x + x2.x + x3.x + x4.x + x5.x;
            sv.y = x0.y + x1.y + x2.y + x3.y + x4.y + x5.y;
            sv.z = x0.z + x1.z + x2.z + x3.z + x4.z + x5.z;
            sv.w = x0.w + x1.w + x2.w + x3.w + x4.w + x5.w;
            *reinterpret_cast<float4*>(&u.interp[fl][d]) = sv;
        }
    }
    __syncthreads();

    // ---- GEMM: out[f][:] = (sum/6) @ W + b ; thread=(rq,jq): rows rq+8i, cols jq*4..+3
    {
        const int jq = tid & 31;
        const int rq = tid >> 5;
        float acc[4][4];
        #pragma unroll
        for (int i = 0; i < 4; ++i)
            #pragma unroll
            for (int j = 0; j < 4; ++j) acc[i][j] = 0.f;

        for (int d4 = 0; d4 < 32; ++d4) {
            float4 wv[4];
            #pragma unroll
            for (int dd = 0; dd < 4; ++dd)
                wv[dd] = *reinterpret_cast<const float4*>(W + (d4 * 4 + dd) * DIM + jq * 4);
            #pragma unroll
            for (int i = 0; i < 4; ++i) {
                const float4 a4 = *reinterpret_cast<const float4*>(&u.interp[rq + 8 * i][d4 * 4]);
                #define GSTEP(av, dd) \
                    acc[i][0] += (av) * wv[dd].x; \
                    acc[i][1] += (av) * wv[dd].y; \
                    acc[i][2] += (av) * wv[dd].z; \
                    acc[i][3] += (av) * wv[dd].w;
                GSTEP(a4.x, 0) GSTEP(a4.y, 1) GSTEP(a4.z, 2) GSTEP(a4.w, 3)
                #undef GSTEP
            }
        }

        const float4 b4 = *reinterpret_cast<const float4*>(bias + jq * 4);
        constexpr float inv6 = 1.0f / 6.0f;
        #pragma unroll
        for (int i = 0; i < 4; ++i) {
            const int fr = forig[rq + 8 * i];
            float4 o;
            o.x = acc[i][0] * inv6 + b4.x;
            o.y = acc[i][1] * inv6 + b4.y;
            o.z = acc[i][2] * inv6 + b4.z;
            o.w = acc[i][3] * inv6 + b4.w;
            *reinterpret_cast<float4*>(out + fr * DIM + jq * 4) = o;
        }
    }
}

extern "C" void kernel_launch(void* const* d_in, const int* in_sizes, int n_in,
                              void* d_out, int out_size, void* d_ws, size_t ws_size,
                              hipStream_t stream) {
    const float* xc = (const float*)d_in[0];
    const float* pc = (const float*)d_in[1];
    const float* pf = (const float*)d_in[2];
    const float* W  = (const float*)d_in[3];
    const float* b  = (const float*)d_in[4];
    float* out = (float*)d_out;

    // ws layout (bytes):
    //   0      cntC/ofsC   512 ints
    //   2048   cntF/ofsF   512 ints
    //   4096   startC      513 ints
    //   6160   startF      513 ints
    //   8224   pts         4000 float4  (64000)
    //   72224  srtF        40000 float4 (640000)  -> total 712224
    int*    cntC   = (int*)d_ws;
    int*    cntF   = (int*)((char*)d_ws + 2048);
    int*    startC = (int*)((char*)d_ws + 4096);
    int*    startF = (int*)((char*)d_ws + 6160);
    float4* pts    = (float4*)((char*)d_ws + 8224);
    float4* srt    = (float4*)((char*)d_ws + 72224);

    hipMemsetAsync(d_ws, 0, 4096, stream);        // zero cntC + cntF
    k_count  <<<172, 256, 0, stream>>>(pc, pf, cntC, cntF);
    k_scan   <<<2, 512, 0, stream>>>(cntC, cntF, startC, startF);
    k_scatter<<<172, 256, 0, stream>>>(pc, pf, cntC, cntF, pts, srt);
    upsampler_fused<<<dim3(NBLK), dim3(NTHR), 0, stream>>>(
        xc, W, b, startC, pts, srt, out);
}

// Round 7
// 58.009 us; speedup vs baseline: 8.2478x; 1.6290x over previous
//
#include <hip/hip_runtime.h>
#include <cstdint>

#define NCOARSE 4000
#define NFINE   40000
#define DIM     128
#define GRES    8
#define CELLH   0.125f
#define CAP_C   40       // coarse slots per cell (lambda=7.8, 11 sigma)
#define CAP_F   160      // fine slots per cell (lambda=78.1, 9 sigma)
#define CHUNKS  5        // CAP_F / 32
#define SCAP    768      // staged-candidate cap (float4)
#define NS      172      // scatter blocks in k_build (ceil(44000/256))
#define NYG     500      // Y-GEMM blocks (4000 rows / 8)

__device__ __forceinline__ uint64_t min64(uint64_t a, uint64_t b) { return a < b ? a : b; }
__device__ __forceinline__ uint64_t max64(uint64_t a, uint64_t b) { return a > b ? a : b; }
__device__ __forceinline__ int cell_coord(float x) {
    int c = (int)(x * 8.0f);
    return c < 0 ? 0 : (c > 7 ? 7 : c);
}

// ---------------- build: direct-slot scatter + Y = xc @ W ----------------
__global__ __launch_bounds__(256) void k_build(const float* __restrict__ pc,
                                               const float* __restrict__ pf,
                                               const float* __restrict__ xc,
                                               const float* __restrict__ W,
                                               int* __restrict__ cntC, int* __restrict__ cntF,
                                               float4* __restrict__ ptsC, float4* __restrict__ srtF,
                                               float* __restrict__ Y) {
    __shared__ float xs[8][DIM];
    const int bid = blockIdx.x, tid = threadIdx.x;
    if (bid < NS) {
        const int i = bid * 256 + tid;
        if (i < NCOARSE) {
            const float x = pc[3*i], y = pc[3*i+1], z = pc[3*i+2];
            const int c = (cell_coord(z) << 6) | (cell_coord(y) << 3) | cell_coord(x);
            const int slot = atomicAdd(&cntC[c], 1);
            if (slot < CAP_C) ptsC[c * CAP_C + slot] = make_float4(x, y, z, __int_as_float(i));
        } else if (i < NCOARSE + NFINE) {
            const int j = i - NCOARSE;
            const float x = pf[3*j], y = pf[3*j+1], z = pf[3*j+2];
            const int c = (cell_coord(z) << 6) | (cell_coord(y) << 3) | cell_coord(x);
            const int slot = atomicAdd(&cntF[c], 1);
            if (slot < CAP_F) srtF[c * CAP_F + slot] = make_float4(x, y, z, __int_as_float(j));
        }
    } else {
        // Y-GEMM tile: 8 rows x 128 cols
        const int g  = bid - NS;
        const int r0 = g * 8;
        reinterpret_cast<float4*>(xs)[tid] =
            reinterpret_cast<const float4*>(xc + r0 * DIM)[tid];
        __syncthreads();
        const int rq = tid >> 5;       // 0..7 row
        const int jq = tid & 31;       // col quad
        float a0 = 0.f, a1 = 0.f, a2 = 0.f, a3 = 0.f;
        #pragma unroll 4
        for (int k = 0; k < DIM; ++k) {
            const float a = xs[rq][k];
            const float4 wv = *reinterpret_cast<const float4*>(W + k * DIM + jq * 4);
            a0 += a * wv.x; a1 += a * wv.y; a2 += a * wv.z; a3 += a * wv.w;
        }
        *reinterpret_cast<float4*>(Y + (r0 + rq) * DIM + jq * 4) = make_float4(a0, a1, a2, a3);
    }
}

// ---------------- main: KNN + gather-mean of Y ----------------
// merge this lane's sorted 7-list with lane^mask's -> sorted top-7 of union
__device__ __forceinline__ void merge_with(uint64_t w[7], int mask) {
    uint64_t v[16];
    #pragma unroll
    for (int r = 0; r < 7; ++r) v[r] = w[r];
    v[7] = ~0ull; v[8] = ~0ull;
    #pragma unroll
    for (int r = 0; r < 7; ++r)
        v[9 + r] = __shfl_xor((unsigned long long)w[6 - r], mask);
    #pragma unroll
    for (int k = 8; k >= 1; k >>= 1) {
        #pragma unroll
        for (int i = 0; i < 16; ++i) {
            if ((i & k) == 0) {
                const uint64_t lo = min64(v[i], v[i | k]);
                v[i | k] = max64(v[i], v[i | k]);
                v[i] = lo;
            }
        }
    }
    #pragma unroll
    for (int r = 0; r < 7; ++r) w[r] = v[r];
}

__device__ __forceinline__ bool done_check(uint64_t k7, float fx, float fy, float fz,
                                           int ix, int iy, int iz, int s) {
    const float d7 = __uint_as_float((uint32_t)(k7 >> 32));
    float clear = 1e30f;
    if (ix - s >= 0) clear = fminf(clear, __fsub_rn(fx, (float)(ix - s) * CELLH));
    if (ix + s <= 6) clear = fminf(clear, __fsub_rn((float)(ix + s + 1) * CELLH, fx));
    if (iy - s >= 0) clear = fminf(clear, __fsub_rn(fy, (float)(iy - s) * CELLH));
    if (iy + s <= 6) clear = fminf(clear, __fsub_rn((float)(iy + s + 1) * CELLH, fy));
    if (iz - s >= 0) clear = fminf(clear, __fsub_rn(fz, (float)(iz - s) * CELLH));
    if (iz + s <= 6) clear = fminf(clear, __fsub_rn((float)(iz + s + 1) * CELLH, fz));
    return d7 < clear * clear * 0.9999f;   // NaN sentinel -> false
}

#define INS(p) { \
    const float ddx = __fsub_rn(fx, (p).x); \
    const float ddy = __fsub_rn(fy, (p).y); \
    const float ddz = __fsub_rn(fz, (p).z); \
    const float d2  = __fadd_rn(__fadd_rn(__fmul_rn(ddx, ddx), __fmul_rn(ddy, ddy)), \
                                __fmul_rn(ddz, ddz)); \
    const uint64_t v = ((uint64_t)__float_as_uint(d2) << 32) | (uint32_t)__float_as_uint((p).w); \
    if (v < own[6]) { \
        own[6] = min64(own[6], max64(own[5], v)); \
        own[5] = min64(own[5], max64(own[4], v)); \
        own[4] = min64(own[4], max64(own[3], v)); \
        own[3] = min64(own[3], max64(own[2], v)); \
        own[2] = min64(own[2], max64(own[1], v)); \
        own[1] = min64(own[1], max64(own[0], v)); \
        own[0] = min64(own[0], v); \
    } }

__global__ __launch_bounds__(256) void k_main(
    const float*  __restrict__ Y,        // [4000][128] = xc @ W
    const float*  __restrict__ bias,
    const int*    __restrict__ cntC,
    const int*    __restrict__ cntF,
    const float4* __restrict__ ptsG,     // fixed-slot coarse
    const float4* __restrict__ srtF,     // fixed-slot fine
    float* __restrict__ out)
{
    __shared__ float4 spts[SCAP];
    __shared__ int rBeg[32], rLds[32];
    __shared__ int idx6[32][6];
    __shared__ int forig[32];
    __shared__ int metaT[1];

    const int bid  = blockIdx.x;
    const int tid  = threadIdx.x;
    const int cell = bid & 511;
    const int chunk= bid >> 9;

    const int ctot = min(cntF[cell], CAP_F);
    const int base = chunk * 32;
    const int npts = min(32, ctot - base);
    if (npts <= 0) return;                      // block-uniform

    const int fl  = tid >> 3;        // 0..31 local fine point
    const int par = tid & 7;         // lane within point-octet
    const int ix = cell & 7, iy = (cell >> 3) & 7, iz = cell >> 6;

    const int srcf = min(fl, npts - 1);
    const float4 fp = srtF[cell * CAP_F + base + srcf];
    const float fx = fp.x, fy = fp.y, fz = fp.z;
    if (par == 0) forig[fl] = (fl < npts) ? __float_as_int(fp.w) : -1;

    const int bx0 = max(ix - 1, 0), bx1 = min(ix + 1, 7);
    const int by0 = max(iy - 1, 0), by1 = min(iy + 1, 7);
    const int bz0 = max(iz - 1, 0), bz1 = min(iz + 1, 7);
    const int nx = bx1 - bx0 + 1, ny = by1 - by0 + 1, nz = bz1 - bz0 + 1;
    const int ncell = nx * ny * nz;             // <= 27

    // neighborhood table + prefix (first wave)
    if (tid < 32) {
        const bool valid = tid < ncell;
        int len = 0, bg = 0;
        if (valid) {
            const int ex = bx0 + tid % nx;
            const int rem = tid / nx;
            const int ey = by0 + rem % ny;
            const int ez = bz0 + rem / ny;
            const int cc = (ez << 6) | (ey << 3) | ex;
            len = min(cntC[cc], CAP_C);
            bg  = cc * CAP_C;
        }
        int x = len;
        #pragma unroll
        for (int o = 1; o < 32; o <<= 1) {
            const int v = __shfl_up(x, o);
            if (tid >= o) x += v;
        }
        rBeg[tid] = valid ? bg : 0;
        rLds[tid] = valid ? (x - len) : 0x7fffffff;
        if (tid == ncell - 1) metaT[0] = x;
    }
    __syncthreads();

    const int total  = metaT[0];
    const bool staged = (total <= SCAP);
    if (staged) {
        for (int g = tid; g < total; g += 256) {
            int lo = 0, hi = 31;
            while (lo < hi) { const int mid = (lo + hi + 1) >> 1; if (rLds[mid] <= g) lo = mid; else hi = mid - 1; }
            spts[g] = ptsG[rBeg[lo] + (g - rLds[lo])];
        }
    }
    __syncthreads();

    uint64_t own[7];
    #pragma unroll
    for (int r = 0; r < 7; ++r) own[r] = ~0ull;

    if (staged) {
        #pragma unroll 4
        for (int i = par; i < total; i += 8) { float4 p = spts[i]; INS(p) }
    } else {
        for (int cz = bz0; cz <= bz1; ++cz)
            for (int cy = by0; cy <= by1; ++cy)
                for (int cx = bx0; cx <= bx1; ++cx) {
                    const int cc = (cz << 6) | (cy << 3) | cx;
                    const int len = min(cntC[cc], CAP_C);
                    const int bg  = cc * CAP_C;
                    for (int i = par; i < len; i += 8) { float4 p = ptsG[bg + i]; INS(p) }
                }
    }

    uint64_t mg[7];
    #pragma unroll
    for (int r = 0; r < 7; ++r) mg[r] = own[r];
    merge_with(mg, 1); merge_with(mg, 2); merge_with(mg, 4);
    bool done = done_check(mg[6], fx, fy, fz, ix, iy, iz, 1);

    for (int s = 2; s <= 7; ++s) {
        if (__all(done)) break;
        if (!done) {
            for (int dz = -s; dz <= s; ++dz) {
                const int cz = iz + dz;
                if ((unsigned)cz >= (unsigned)GRES) continue;
                const bool fz_face = (dz == -s) | (dz == s);
                for (int dy = -s; dy <= s; ++dy) {
                    const int cy = iy + dy;
                    if ((unsigned)cy >= (unsigned)GRES) continue;
                    const bool yz_face = fz_face | (dy == -s) | (dy == s);
                    for (int dx = -s; dx <= s; ++dx) {
                        if (!yz_face && dx > -s && dx < s) continue;
                        const int cx = ix + dx;
                        if ((unsigned)cx >= (unsigned)GRES) continue;
                        if (cx >= bx0 && cx <= bx1 && cy >= by0 && cy <= by1 &&
                            cz >= bz0 && cz <= bz1) continue;   // already scanned
                        const int cc = (cz << 6) | (cy << 3) | cx;
                        const int len = min(cntC[cc], CAP_C);
                        const int bg  = cc * CAP_C;
                        for (int i = par; i < len; i += 8) { float4 p = ptsG[bg + i]; INS(p) }
                    }
                }
            }
            #pragma unroll
            for (int r = 0; r < 7; ++r) mg[r] = own[r];
            merge_with(mg, 1); merge_with(mg, 2); merge_with(mg, 4);
            done = done_check(mg[6], fx, fy, fz, ix, iy, iz, s);
        }
    }

    if (par == 0) {
        // 6th/7th sqrt tie repair (reference sorts by f32 sqrt, stable)
        int i5 = (int)(uint32_t)mg[5];
        const int i6 = (int)(uint32_t)mg[6];
        const float d5 = sqrtf(__uint_as_float((uint32_t)(mg[5] >> 32)));
        const float d6 = sqrtf(__uint_as_float((uint32_t)(mg[6] >> 32)));
        if (d5 == d6 && i6 < i5) i5 = i6;
        idx6[fl][0] = (int)(uint32_t)mg[0];
        idx6[fl][1] = (int)(uint32_t)mg[1];
        idx6[fl][2] = (int)(uint32_t)mg[2];
        idx6[fl][3] = (int)(uint32_t)mg[3];
        idx6[fl][4] = (int)(uint32_t)mg[4];
        idx6[fl][5] = i5;
    }
    __syncthreads();

    // ---- epilogue: out[f] = mean(Y[idx6]) + b ; lane par covers 16 dims
    {
        const int fr = forig[fl];
        if (fr >= 0) {
            const int id0 = idx6[fl][0], id1 = idx6[fl][1], id2 = idx6[fl][2];
            const int id3 = idx6[fl][3], id4 = idx6[fl][4], id5 = idx6[fl][5];
            constexpr float inv6 = 1.0f / 6.0f;
            #pragma unroll
            for (int k = 0; k < 4; ++k) {
                const int q = (k * 8 + par) * 4;     // float offset, contiguous across par
                const float4 y0 = *reinterpret_cast<const float4*>(Y + id0 * DIM + q);
                const float4 y1 = *reinterpret_cast<const float4*>(Y + id1 * DIM + q);
                const float4 y2 = *reinterpret_cast<const float4*>(Y + id2 * DIM + q);
                const float4 y3 = *reinterpret_cast<const float4*>(Y + id3 * DIM + q);
                const float4 y4 = *reinterpret_cast<const float4*>(Y + id4 * DIM + q);
                const float4 y5 = *reinterpret_cast<const float4*>(Y + id5 * DIM + q);
                const float4 bv = *reinterpret_cast<const float4*>(bias + q);
                float4 o;
                o.x = (y0.x + y1.x + y2.x + y3.x + y4.x + y5.x) * inv6 + bv.x;
                o.y = (y0.y + y1.y + y2.y + y3.y + y4.y + y5.y) * inv6 + bv.y;
                o.z = (y0.z + y1.z + y2.z + y3.z + y4.z + y5.z) * inv6 + bv.z;
                o.w = (y0.w + y1.w + y2.w + y3.w + y4.w + y5.w) * inv6 + bv.w;
                *reinterpret_cast<float4*>(out + fr * DIM + q) = o;
            }
        }
    }
}

extern "C" void kernel_launch(void* const* d_in, const int* in_sizes, int n_in,
                              void* d_out, int out_size, void* d_ws, size_t ws_size,
                              hipStream_t stream) {
    const float* xc = (const float*)d_in[0];
    const float* pc = (const float*)d_in[1];
    const float* pf = (const float*)d_in[2];
    const float* W  = (const float*)d_in[3];
    const float* b  = (const float*)d_in[4];
    float* out = (float*)d_out;

    // ws layout (bytes):
    //   0        cntC   512 ints (2048)
    //   2048     cntF   512 ints (2048)
    //   4096     ptsC   512*40 float4  (327680)
    //   331776   srtF   512*160 float4 (1310720)
    //   1642496  Y      4000*128 f32   (2048000)   total 3690496
    int*    cntC = (int*)d_ws;
    int*    cntF = (int*)((char*)d_ws + 2048);
    float4* ptsC = (float4*)((char*)d_ws + 4096);
    float4* srtF = (float4*)((char*)d_ws + 331776);
    float*  Y    = (float*)((char*)d_ws + 1642496);

    hipMemsetAsync(d_ws, 0, 4096, stream);    // zero cntC + cntF
    k_build<<<dim3(NS + NYG), dim3(256), 0, stream>>>(pc, pf, xc, W, cntC, cntF, ptsC, srtF, Y);
    k_main <<<dim3(512 * CHUNKS), dim3(256), 0, stream>>>(Y, b, cntC, cntF, ptsC, srtF, out);
}

// Round 8
// 57.846 us; speedup vs baseline: 8.2711x; 1.0028x over previous
//
#include <hip/hip_runtime.h>
#include <cstdint>

#define NCOARSE 4000
#define NFINE   40000
#define DIM     128
#define GRES    8
#define CELLH   0.125f
#define CAP_C   40       // coarse slots per cell (lambda=7.8, 11 sigma)
#define CAP_F   160      // fine slots per cell (lambda=78.1, 9 sigma)
#define CHUNKS  5        // CAP_F / 32
#define SCAP    768      // staged-candidate cap (float4)
#define NS      172      // scatter blocks in k_build (ceil(44000/256))
#define NYG     500      // Y-GEMM blocks (4000 rows / 8)

__device__ __forceinline__ uint64_t min64(uint64_t a, uint64_t b) { return a < b ? a : b; }
__device__ __forceinline__ uint64_t max64(uint64_t a, uint64_t b) { return a > b ? a : b; }
__device__ __forceinline__ int cell_coord(float x) {
    int c = (int)(x * 8.0f);
    return c < 0 ? 0 : (c > 7 ? 7 : c);
}

// ---------------- zero the two 512-int counter arrays (replaces hipMemsetAsync) ----
__global__ __launch_bounds__(256) void k_zero(int* __restrict__ p) {
    p[blockIdx.x * 256 + threadIdx.x] = 0;
}

// ---------------- build: direct-slot scatter + Y = xc @ W ----------------
__global__ __launch_bounds__(256) void k_build(const float* __restrict__ pc,
                                               const float* __restrict__ pf,
                                               const float* __restrict__ xc,
                                               const float* __restrict__ W,
                                               int* __restrict__ cntC, int* __restrict__ cntF,
                                               float4* __restrict__ ptsC, float4* __restrict__ srtF,
                                               float* __restrict__ Y) {
    __shared__ float xs[8][DIM];
    const int bid = blockIdx.x, tid = threadIdx.x;
    if (bid < NS) {
        const int i = bid * 256 + tid;
        if (i < NCOARSE) {
            const float x = pc[3*i], y = pc[3*i+1], z = pc[3*i+2];
            const int c = (cell_coord(z) << 6) | (cell_coord(y) << 3) | cell_coord(x);
            const int slot = atomicAdd(&cntC[c], 1);
            if (slot < CAP_C) ptsC[c * CAP_C + slot] = make_float4(x, y, z, __int_as_float(i));
        } else if (i < NCOARSE + NFINE) {
            const int j = i - NCOARSE;
            const float x = pf[3*j], y = pf[3*j+1], z = pf[3*j+2];
            const int c = (cell_coord(z) << 6) | (cell_coord(y) << 3) | cell_coord(x);
            const int slot = atomicAdd(&cntF[c], 1);
            if (slot < CAP_F) srtF[c * CAP_F + slot] = make_float4(x, y, z, __int_as_float(j));
        }
    } else {
        // Y-GEMM tile: 8 rows x 128 cols
        const int g  = bid - NS;
        const int r0 = g * 8;
        reinterpret_cast<float4*>(xs)[tid] =
            reinterpret_cast<const float4*>(xc + r0 * DIM)[tid];
        __syncthreads();
        const int rq = tid >> 5;       // 0..7 row
        const int jq = tid & 31;       // col quad
        float a0 = 0.f, a1 = 0.f, a2 = 0.f, a3 = 0.f;
        #pragma unroll 4
        for (int k = 0; k < DIM; ++k) {
            const float a = xs[rq][k];
            const float4 wv = *reinterpret_cast<const float4*>(W + k * DIM + jq * 4);
            a0 += a * wv.x; a1 += a * wv.y; a2 += a * wv.z; a3 += a * wv.w;
        }
        *reinterpret_cast<float4*>(Y + (r0 + rq) * DIM + jq * 4) = make_float4(a0, a1, a2, a3);
    }
}

// ---------------- main: KNN + gather-mean of Y ----------------
// merge this lane's sorted 7-list with lane^mask's -> sorted top-7 of union
__device__ __forceinline__ void merge_with(uint64_t w[7], int mask) {
    uint64_t v[16];
    #pragma unroll
    for (int r = 0; r < 7; ++r) v[r] = w[r];
    v[7] = ~0ull; v[8] = ~0ull;
    #pragma unroll
    for (int r = 0; r < 7; ++r)
        v[9 + r] = __shfl_xor((unsigned long long)w[6 - r], mask);
    #pragma unroll
    for (int k = 8; k >= 1; k >>= 1) {
        #pragma unroll
        for (int i = 0; i < 16; ++i) {
            if ((i & k) == 0) {
                const uint64_t lo = min64(v[i], v[i | k]);
                v[i | k] = max64(v[i], v[i | k]);
                v[i] = lo;
            }
        }
    }
    #pragma unroll
    for (int r = 0; r < 7; ++r) w[r] = v[r];
}

__device__ __forceinline__ bool done_check(uint64_t k7, float fx, float fy, float fz,
                                           int ix, int iy, int iz, int s) {
    const float d7 = __uint_as_float((uint32_t)(k7 >> 32));
    float clear = 1e30f;
    if (ix - s >= 0) clear = fminf(clear, __fsub_rn(fx, (float)(ix - s) * CELLH));
    if (ix + s <= 6) clear = fminf(clear, __fsub_rn((float)(ix + s + 1) * CELLH, fx));
    if (iy - s >= 0) clear = fminf(clear, __fsub_rn(fy, (float)(iy - s) * CELLH));
    if (iy + s <= 6) clear = fminf(clear, __fsub_rn((float)(iy + s + 1) * CELLH, fy));
    if (iz - s >= 0) clear = fminf(clear, __fsub_rn(fz, (float)(iz - s) * CELLH));
    if (iz + s <= 6) clear = fminf(clear, __fsub_rn((float)(iz + s + 1) * CELLH, fz));
    return d7 < clear * clear * 0.9999f;   // NaN sentinel -> false
}

#define INS(p) { \
    const float ddx = __fsub_rn(fx, (p).x); \
    const float ddy = __fsub_rn(fy, (p).y); \
    const float ddz = __fsub_rn(fz, (p).z); \
    const float d2  = __fadd_rn(__fadd_rn(__fmul_rn(ddx, ddx), __fmul_rn(ddy, ddy)), \
                                __fmul_rn(ddz, ddz)); \
    const uint64_t v = ((uint64_t)__float_as_uint(d2) << 32) | (uint32_t)__float_as_uint((p).w); \
    if (v < own[6]) { \
        own[6] = min64(own[6], max64(own[5], v)); \
        own[5] = min64(own[5], max64(own[4], v)); \
        own[4] = min64(own[4], max64(own[3], v)); \
        own[3] = min64(own[3], max64(own[2], v)); \
        own[2] = min64(own[2], max64(own[1], v)); \
        own[1] = min64(own[1], max64(own[0], v)); \
        own[0] = min64(own[0], v); \
    } }

__global__ __launch_bounds__(256) void k_main(
    const float*  __restrict__ Y,        // [4000][128] = xc @ W
    const float*  __restrict__ bias,
    const int*    __restrict__ cntC,
    const int*    __restrict__ cntF,
    const float4* __restrict__ ptsG,     // fixed-slot coarse
    const float4* __restrict__ srtF,     // fixed-slot fine
    float* __restrict__ out)
{
    __shared__ float4 spts[SCAP];
    __shared__ int rBeg[32], rLds[32];
    __shared__ int idx6[32][6];
    __shared__ int forig[32];
    __shared__ int metaT[1];

    const int bid  = blockIdx.x;
    const int tid  = threadIdx.x;
    const int cell = bid & 511;
    const int chunk= bid >> 9;

    const int ctot = min(cntF[cell], CAP_F);
    const int base = chunk * 32;
    const int npts = min(32, ctot - base);
    if (npts <= 0) return;                      // block-uniform

    const int fl  = tid >> 3;        // 0..31 local fine point
    const int par = tid & 7;         // lane within point-octet
    const int ix = cell & 7, iy = (cell >> 3) & 7, iz = cell >> 6;

    const int srcf = min(fl, npts - 1);
    const float4 fp = srtF[cell * CAP_F + base + srcf];
    const float fx = fp.x, fy = fp.y, fz = fp.z;
    if (par == 0) forig[fl] = (fl < npts) ? __float_as_int(fp.w) : -1;

    const int bx0 = max(ix - 1, 0), bx1 = min(ix + 1, 7);
    const int by0 = max(iy - 1, 0), by1 = min(iy + 1, 7);
    const int bz0 = max(iz - 1, 0), bz1 = min(iz + 1, 7);
    const int nx = bx1 - bx0 + 1, ny = by1 - by0 + 1, nz = bz1 - bz0 + 1;
    const int ncell = nx * ny * nz;             // <= 27

    // neighborhood table + prefix (first wave)
    if (tid < 32) {
        const bool valid = tid < ncell;
        int len = 0, bg = 0;
        if (valid) {
            const int ex = bx0 + tid % nx;
            const int rem = tid / nx;
            const int ey = by0 + rem % ny;
            const int ez = bz0 + rem / ny;
            const int cc = (ez << 6) | (ey << 3) | ex;
            len = min(cntC[cc], CAP_C);
            bg  = cc * CAP_C;
        }
        int x = len;
        #pragma unroll
        for (int o = 1; o < 32; o <<= 1) {
            const int v = __shfl_up(x, o);
            if (tid >= o) x += v;
        }
        rBeg[tid] = valid ? bg : 0;
        rLds[tid] = valid ? (x - len) : 0x7fffffff;
        if (tid == ncell - 1) metaT[0] = x;
    }
    __syncthreads();

    const int total  = metaT[0];
    const bool staged = (total <= SCAP);
    if (staged) {
        for (int g = tid; g < total; g += 256) {
            int lo = 0, hi = 31;
            while (lo < hi) { const int mid = (lo + hi + 1) >> 1; if (rLds[mid] <= g) lo = mid; else hi = mid - 1; }
            spts[g] = ptsG[rBeg[lo] + (g - rLds[lo])];
        }
    }
    __syncthreads();

    uint64_t own[7];
    #pragma unroll
    for (int r = 0; r < 7; ++r) own[r] = ~0ull;

    if (staged) {
        #pragma unroll 4
        for (int i = par; i < total; i += 8) { float4 p = spts[i]; INS(p) }
    } else {
        for (int cz = bz0; cz <= bz1; ++cz)
            for (int cy = by0; cy <= by1; ++cy)
                for (int cx = bx0; cx <= bx1; ++cx) {
                    const int cc = (cz << 6) | (cy << 3) | cx;
                    const int len = min(cntC[cc], CAP_C);
                    const int bg  = cc * CAP_C;
                    for (int i = par; i < len; i += 8) { float4 p = ptsG[bg + i]; INS(p) }
                }
    }

    uint64_t mg[7];
    #pragma unroll
    for (int r = 0; r < 7; ++r) mg[r] = own[r];
    merge_with(mg, 1); merge_with(mg, 2); merge_with(mg, 4);
    bool done = done_check(mg[6], fx, fy, fz, ix, iy, iz, 1);

    for (int s = 2; s <= 7; ++s) {
        if (__all(done)) break;
        if (!done) {
            for (int dz = -s; dz <= s; ++dz) {
                const int cz = iz + dz;
                if ((unsigned)cz >= (unsigned)GRES) continue;
                const bool fz_face = (dz == -s) | (dz == s);
                for (int dy = -s; dy <= s; ++dy) {
                    const int cy = iy + dy;
                    if ((unsigned)cy >= (unsigned)GRES) continue;
                    const bool yz_face = fz_face | (dy == -s) | (dy == s);
                    for (int dx = -s; dx <= s; ++dx) {
                        if (!yz_face && dx > -s && dx < s) continue;
                        const int cx = ix + dx;
                        if ((unsigned)cx >= (unsigned)GRES) continue;
                        if (cx >= bx0 && cx <= bx1 && cy >= by0 && cy <= by1 &&
                            cz >= bz0 && cz <= bz1) continue;   // already scanned
                        const int cc = (cz << 6) | (cy << 3) | cx;
                        const int len = min(cntC[cc], CAP_C);
                        const int bg  = cc * CAP_C;
                        for (int i = par; i < len; i += 8) { float4 p = ptsG[bg + i]; INS(p) }
                    }
                }
            }
            #pragma unroll
            for (int r = 0; r < 7; ++r) mg[r] = own[r];
            merge_with(mg, 1); merge_with(mg, 2); merge_with(mg, 4);
            done = done_check(mg[6], fx, fy, fz, ix, iy, iz, s);
        }
    }

    if (par == 0) {
        // 6th/7th sqrt tie repair (reference sorts by f32 sqrt, stable)
        int i5 = (int)(uint32_t)mg[5];
        const int i6 = (int)(uint32_t)mg[6];
        const float d5 = sqrtf(__uint_as_float((uint32_t)(mg[5] >> 32)));
        const float d6 = sqrtf(__uint_as_float((uint32_t)(mg[6] >> 32)));
        if (d5 == d6 && i6 < i5) i5 = i6;
        idx6[fl][0] = (int)(uint32_t)mg[0];
        idx6[fl][1] = (int)(uint32_t)mg[1];
        idx6[fl][2] = (int)(uint32_t)mg[2];
        idx6[fl][3] = (int)(uint32_t)mg[3];
        idx6[fl][4] = (int)(uint32_t)mg[4];
        idx6[fl][5] = i5;
    }
    __syncthreads();

    // ---- epilogue: out[f] = mean(Y[idx6]) + b ; lane par covers 16 dims
    {
        const int fr = forig[fl];
        if (fr >= 0) {
            const int id0 = idx6[fl][0], id1 = idx6[fl][1], id2 = idx6[fl][2];
            const int id3 = idx6[fl][3], id4 = idx6[fl][4], id5 = idx6[fl][5];
            constexpr float inv6 = 1.0f / 6.0f;
            #pragma unroll
            for (int k = 0; k < 4; ++k) {
                const int q = (k * 8 + par) * 4;     // float offset, contiguous across par
                const float4 y0 = *reinterpret_cast<const float4*>(Y + id0 * DIM + q);
                const float4 y1 = *reinterpret_cast<const float4*>(Y + id1 * DIM + q);
                const float4 y2 = *reinterpret_cast<const float4*>(Y + id2 * DIM + q);
                const float4 y3 = *reinterpret_cast<const float4*>(Y + id3 * DIM + q);
                const float4 y4 = *reinterpret_cast<const float4*>(Y + id4 * DIM + q);
                const float4 y5 = *reinterpret_cast<const float4*>(Y + id5 * DIM + q);
                const float4 bv = *reinterpret_cast<const float4*>(bias + q);
                float4 o;
                o.x = (y0.x + y1.x + y2.x + y3.x + y4.x + y5.x) * inv6 + bv.x;
                o.y = (y0.y + y1.y + y2.y + y3.y + y4.y + y5.y) * inv6 + bv.y;
                o.z = (y0.z + y1.z + y2.z + y3.z + y4.z + y5.z) * inv6 + bv.z;
                o.w = (y0.w + y1.w + y2.w + y3.w + y4.w + y5.w) * inv6 + bv.w;
                *reinterpret_cast<float4*>(out + fr * DIM + q) = o;
            }
        }
    }
}

extern "C" void kernel_launch(void* const* d_in, const int* in_sizes, int n_in,
                              void* d_out, int out_size, void* d_ws, size_t ws_size,
                              hipStream_t stream) {
    const float* xc = (const float*)d_in[0];
    const float* pc = (const float*)d_in[1];
    const float* pf = (const float*)d_in[2];
    const float* W  = (const float*)d_in[3];
    const float* b  = (const float*)d_in[4];
    float* out = (float*)d_out;

    // ws layout (bytes):
    //   0        cntC   512 ints (2048)
    //   2048     cntF   512 ints (2048)
    //   4096     ptsC   512*40 float4  (327680)
    //   331776   srtF   512*160 float4 (1310720)
    //   1642496  Y      4000*128 f32   (2048000)   total 3690496
    int*    cntC = (int*)d_ws;
    int*    cntF = (int*)((char*)d_ws + 2048);
    float4* ptsC = (float4*)((char*)d_ws + 4096);
    float4* srtF = (float4*)((char*)d_ws + 331776);
    float*  Y    = (float*)((char*)d_ws + 1642496);

    k_zero <<<dim3(4),          dim3(256), 0, stream>>>((int*)d_ws);   // zero cntC + cntF
    k_build<<<dim3(NS + NYG),   dim3(256), 0, stream>>>(pc, pf, xc, W, cntC, cntF, ptsC, srtF, Y);
    k_main <<<dim3(512 * CHUNKS), dim3(256), 0, stream>>>(Y, b, cntC, cntF, ptsC, srtF, out);
}